// Round 1
// baseline (1765.583 us; speedup 1.0000x reference)
//
#include <hip/hip_runtime.h>

#define NN 50000
#define NE 800000
#define NR 6
#define FD 128

// ---------------------------------------------------------------------------
// Edge scatter: pre_agg[r,dst,:] += node_h[src,:], deg[r,dst] += 1
// 32 lanes (float4 each) per edge.
// ---------------------------------------------------------------------------
__global__ __launch_bounds__(256) void k_edge_scatter(
    const float* __restrict__ node_h,
    const int* __restrict__ esrc,
    const int* __restrict__ edst,
    const int* __restrict__ erel,
    float* __restrict__ pre_agg,   // [NR][NN][FD]
    float* __restrict__ deg)       // [NR][NN]
{
    unsigned idx = blockIdx.x * 256u + threadIdx.x;
    unsigned e = idx >> 5;
    unsigned c = idx & 31u;
    if (e >= NE) return;
    int s = esrc[e], d = edst[e], r = erel[e];
    float4 v = ((const float4*)(node_h + (size_t)s * FD))[c];
    float* dst = pre_agg + ((size_t)r * NN + d) * FD + c * 4;
    atomicAdd(dst + 0, v.x);
    atomicAdd(dst + 1, v.y);
    atomicAdd(dst + 2, v.z);
    atomicAdd(dst + 3, v.w);
    if (c == 0) atomicAdd(deg + (size_t)r * NN + d, 1.0f);
}

// ---------------------------------------------------------------------------
// Per-relation GEMM, in place:
//   pre_agg[r,n,:] = (pre_agg[r,n,:] / (1+deg[r,n])) @ weight[r]
// Tile: 64 rows x 128 cols, K=128 in 2 tiles of 64. LDS ~49 KB.
// ---------------------------------------------------------------------------
__global__ __launch_bounds__(256) void k_rel_gemm(
    float* __restrict__ pre_agg,
    const float* __restrict__ weight,   // [NR][FD][FD] (k-major: [f][o])
    const float* __restrict__ deg)
{
    __shared__ float As[64 * 65];    // [row][kk], pad 65 -> 2-way reads (free)
    __shared__ float Bs[64 * 128];   // [kk][o], straight copy
    const int r  = blockIdx.y;
    const int n0 = blockIdx.x * 64;
    const int t  = threadIdx.x;
    const int tm = t & 15;           // 4 rows each
    const int tn = t >> 4;           // 8 cols each

    float acc[4][8];
#pragma unroll
    for (int i = 0; i < 4; ++i)
#pragma unroll
        for (int j = 0; j < 8; ++j) acc[i][j] = 0.f;

    const float* A = pre_agg + (size_t)r * NN * FD;

    for (int kt = 0; kt < 2; ++kt) {
        // stage B: rows [kt*64, kt*64+64) of weight[r] — linear float4 copy
        {
            const float4* w4 = (const float4*)(weight + (size_t)r * FD * FD + kt * 64 * FD);
            float4* b4 = (float4*)Bs;
#pragma unroll
            for (int i = 0; i < 8; ++i) b4[i * 256 + t] = w4[i * 256 + t];
        }
        // stage A (64 rows x 64 k), scaled by 1/(1+deg)
#pragma unroll
        for (int i = 0; i < 4; ++i) {
            int flat = i * 1024 + t * 4;
            int row = flat >> 6;
            int k = flat & 63;
            int n = n0 + row;
            float4 v = make_float4(0.f, 0.f, 0.f, 0.f);
            float sc = 0.f;
            if (n < NN) {
                v = *(const float4*)(A + (size_t)n * FD + kt * 64 + k);
                sc = 1.0f / (1.0f + deg[r * NN + n]);
            }
            float* p = As + row * 65 + k;
            p[0] = v.x * sc; p[1] = v.y * sc; p[2] = v.z * sc; p[3] = v.w * sc;
        }
        __syncthreads();

#pragma unroll 4
        for (int k = 0; k < 64; ++k) {
            float aa[4];
#pragma unroll
            for (int i = 0; i < 4; ++i) aa[i] = As[(4 * tm + i) * 65 + k];
            float4 blo = *(const float4*)(Bs + k * 128 + 8 * tn);
            float4 bhi = *(const float4*)(Bs + k * 128 + 8 * tn + 4);
            float bb[8] = {blo.x, blo.y, blo.z, blo.w, bhi.x, bhi.y, bhi.z, bhi.w};
#pragma unroll
            for (int i = 0; i < 4; ++i)
#pragma unroll
                for (int j = 0; j < 8; ++j) acc[i][j] += aa[i] * bb[j];
        }
        __syncthreads();
    }

    // write back in place (block only writes rows it staged; reads are done)
    float* C = pre_agg + (size_t)r * NN * FD;
#pragma unroll
    for (int i = 0; i < 4; ++i) {
        int n = n0 + 4 * tm + i;
        if (n < NN) {
            float4* c4 = (float4*)(C + (size_t)n * FD + 8 * tn);
            c4[0] = make_float4(acc[i][0], acc[i][1], acc[i][2], acc[i][3]);
            c4[1] = make_float4(acc[i][4], acc[i][5], acc[i][6], acc[i][7]);
        }
    }
}

// ---------------------------------------------------------------------------
// Attention: per node, softmax over 6 relations (two heads), form
// v1 = sum_r s1[r]*op[n,r,:], v2 = sum_r s2[r]*op[n,r,:]; write v1 over
// hrs[0][n][:], v2 over hrs[1][n][:] (read-before-write in same wave).
// One wave per node.
// ---------------------------------------------------------------------------
__global__ __launch_bounds__(256) void k_attn(
    float* __restrict__ hrs,        // [NR][NN][FD]
    const float* __restrict__ att1,
    const float* __restrict__ att2)
{
    const int t = threadIdx.x;
    const int lane = t & 63;
    const int w = t >> 6;
    const int wid = blockIdx.x * 4 + w;
    const int nw = gridDim.x * 4;
    const float a1l = att1[lane], a1h = att1[lane + 64];
    const float a2l = att2[lane], a2h = att2[lane + 64];

    for (int n = wid; n < NN; n += nw) {
        float ol[NR], oh[NR], p1[NR], p2[NR];
#pragma unroll
        for (int r = 0; r < NR; ++r) {
            const float* row = hrs + ((size_t)r * NN + n) * FD;
            ol[r] = row[lane];
            oh[r] = row[lane + 64];
            p1[r] = ol[r] * a1l + oh[r] * a1h;
            p2[r] = ol[r] * a2l + oh[r] * a2h;
        }
#pragma unroll
        for (int off = 32; off > 0; off >>= 1) {
#pragma unroll
            for (int r = 0; r < NR; ++r) {
                p1[r] += __shfl_xor(p1[r], off, 64);
                p2[r] += __shfl_xor(p2[r], off, 64);
            }
        }
        float m1 = p1[0], m2 = p2[0];
#pragma unroll
        for (int r = 1; r < NR; ++r) { m1 = fmaxf(m1, p1[r]); m2 = fmaxf(m2, p2[r]); }
        float s1[NR], s2[NR], d1 = 0.f, d2 = 0.f;
#pragma unroll
        for (int r = 0; r < NR; ++r) {
            s1[r] = __expf(p1[r] - m1); d1 += s1[r];
            s2[r] = __expf(p2[r] - m2); d2 += s2[r];
        }
        d1 = 1.0f / d1; d2 = 1.0f / d2;
        float v1l = 0.f, v1h = 0.f, v2l = 0.f, v2h = 0.f;
#pragma unroll
        for (int r = 0; r < NR; ++r) {
            float w1 = s1[r] * d1, w2 = s2[r] * d2;
            v1l += w1 * ol[r]; v1h += w1 * oh[r];
            v2l += w2 * ol[r]; v2h += w2 * oh[r];
        }
        float* q0 = hrs + (size_t)n * FD;                // row r=0 -> v1
        float* q1 = hrs + ((size_t)NN + n) * FD;         // row r=1 -> v2
        q0[lane] = v1l; q0[lane + 64] = v1h;
        q1[lane] = v2l; q1[lane + 64] = v2h;
    }
}

// ---------------------------------------------------------------------------
// Output GEMM: out[n,o] = sum_{j<128} V1[n,j]*Wc[o,j]
//                       + sum_{j<128} V2[n,j]*Wc[o,128+j] + NR*bc[o]
// V1 lives at hrs rows r=0, V2 at r=1. K=256 in 4 tiles of 64. LDS ~50 KB.
// ---------------------------------------------------------------------------
__global__ __launch_bounds__(256) void k_out_gemm(
    const float* __restrict__ V,     // pre_agg base
    const float* __restrict__ Wc,    // [FD][2*FD]
    const float* __restrict__ bc,    // [FD]
    float* __restrict__ out)         // [NN][FD]
{
    __shared__ float As[64 * 65];     // [row][kk]
    __shared__ float Bs[64 * 132];    // [kk][o], pad 132 keeps float4 reads clean
    const int n0 = blockIdx.x * 64;
    const int t  = threadIdx.x;
    const int tm = t & 15;
    const int tn = t >> 4;

    float acc[4][8];
#pragma unroll
    for (int i = 0; i < 4; ++i)
#pragma unroll
        for (int j = 0; j < 8; ++j) acc[i][j] = 0.f;

    for (int kt = 0; kt < 4; ++kt) {
        // stage A: V-half (kt>>1), columns (kt&1)*64 ..
        const float* Abase = V + (size_t)(kt >> 1) * NN * FD + (kt & 1) * 64;
#pragma unroll
        for (int i = 0; i < 4; ++i) {
            int flat = i * 1024 + t * 4;
            int row = flat >> 6;
            int k = flat & 63;
            int n = n0 + row;
            float4 v = make_float4(0.f, 0.f, 0.f, 0.f);
            if (n < NN) v = *(const float4*)(Abase + (size_t)n * FD + k);
            float* p = As + row * 65 + k;
            p[0] = v.x; p[1] = v.y; p[2] = v.z; p[3] = v.w;
        }
        // stage B transposed: Bs[kk][o] = Wc[o][kt*64+kk]
#pragma unroll
        for (int i = 0; i < 8; ++i) {
            int flat4 = i * 256 + t;          // 0..2047
            int o = flat4 >> 4;               // 0..127
            int j4 = flat4 & 15;              // 0..15
            float4 v = *(const float4*)(Wc + (size_t)o * 256 + kt * 64 + j4 * 4);
            float* p = Bs + (j4 * 4) * 132 + o;
            p[0] = v.x; p[132] = v.y; p[264] = v.z; p[396] = v.w;
        }
        __syncthreads();

#pragma unroll 4
        for (int k = 0; k < 64; ++k) {
            float aa[4];
#pragma unroll
            for (int i = 0; i < 4; ++i) aa[i] = As[(4 * tm + i) * 65 + k];
            float4 blo = *(const float4*)(Bs + k * 132 + 8 * tn);
            float4 bhi = *(const float4*)(Bs + k * 132 + 8 * tn + 4);
            float bb[8] = {blo.x, blo.y, blo.z, blo.w, bhi.x, bhi.y, bhi.z, bhi.w};
#pragma unroll
            for (int i = 0; i < 4; ++i)
#pragma unroll
                for (int j = 0; j < 8; ++j) acc[i][j] += aa[i] * bb[j];
        }
        __syncthreads();
    }

#pragma unroll
    for (int i = 0; i < 4; ++i) {
        int n = n0 + 4 * tm + i;
        if (n < NN) {
            float* o0 = out + (size_t)n * FD + 8 * tn;
#pragma unroll
            for (int j = 0; j < 8; ++j) o0[j] = acc[i][j] + 6.0f * bc[8 * tn + j];
        }
    }
}

// ---------------------------------------------------------------------------
extern "C" void kernel_launch(void* const* d_in, const int* in_sizes, int n_in,
                              void* d_out, int out_size, void* d_ws, size_t ws_size,
                              hipStream_t stream)
{
    const float* node_h = (const float*)d_in[0];
    const float* weight = (const float*)d_in[1];
    const float* att1   = (const float*)d_in[2];
    const float* att2   = (const float*)d_in[3];
    const float* Wc     = (const float*)d_in[4];
    const float* bc     = (const float*)d_in[5];
    const int* esrc = (const int*)d_in[6];
    const int* edst = (const int*)d_in[7];
    const int* erel = (const int*)d_in[8];
    float* out = (float*)d_out;

    float* pre_agg = (float*)d_ws;                       // NR*NN*FD floats
    float* deg = pre_agg + (size_t)NR * NN * FD;         // NR*NN floats

    size_t zero_bytes = ((size_t)NR * NN * FD + (size_t)NR * NN) * sizeof(float);
    hipMemsetAsync(d_ws, 0, zero_bytes, stream);

    k_edge_scatter<<<(NE * 32 + 255) / 256, 256, 0, stream>>>(
        node_h, esrc, edst, erel, pre_agg, deg);

    dim3 g1((NN + 63) / 64, NR);
    k_rel_gemm<<<g1, 256, 0, stream>>>(pre_agg, weight, deg);

    k_attn<<<256, 256, 0, stream>>>(pre_agg, att1, att2);

    k_out_gemm<<<(NN + 63) / 64, 256, 0, stream>>>(pre_agg, Wc, bc, out);

    hipMemcpyAsync(out + (size_t)NN * FD, weight,
                   (size_t)NR * FD * FD * sizeof(float),
                   hipMemcpyDeviceToDevice, stream);
}

// Round 2
// 667.538 us; speedup vs baseline: 2.6449x; 2.6449x over previous
//
#include <hip/hip_runtime.h>

#define NN 50000
#define NE 800000
#define NR 6
#define FD 128

// ---------------------------------------------------------------------------
// Counting-sort pipeline: histogram by dst -> scan -> place packed edges.
// ---------------------------------------------------------------------------
__global__ __launch_bounds__(256) void k_hist(
    const int* __restrict__ edst, int* __restrict__ cnt)
{
    int e = blockIdx.x * 256 + threadIdx.x;
    if (e < NE) atomicAdd(cnt + edst[e], 1);
}

// Single-workgroup exclusive scan over NN bins. cursor may alias cnt.
__global__ __launch_bounds__(1024) void k_scan(
    const int* __restrict__ cnt, int* __restrict__ offs, int* __restrict__ cursor)
{
    __shared__ int partial[1024];
    const int t = threadIdx.x;
    const int per = (NN + 1023) / 1024;   // 49
    const int base = t * per;
    int sum = 0;
#pragma unroll 4
    for (int i = 0; i < per; ++i) {
        int idx = base + i;
        if (idx < NN) sum += cnt[idx];
    }
    partial[t] = sum;
    __syncthreads();
    for (int off = 1; off < 1024; off <<= 1) {
        int x = (t >= off) ? partial[t - off] : 0;
        __syncthreads();
        if (t >= off) partial[t] += x;
        __syncthreads();
    }
    int run = partial[t] - sum;   // exclusive prefix of this chunk
    for (int i = 0; i < per; ++i) {
        int idx = base + i;
        if (idx < NN) {
            int c = cnt[idx];     // read BEFORE overwriting (cursor aliases cnt)
            offs[idx] = run;
            cursor[idx] = run;
            run += c;
        }
    }
    if (t == 1023) offs[NN] = NE;
}

__global__ __launch_bounds__(256) void k_place(
    const int* __restrict__ esrc, const int* __restrict__ edst,
    const int* __restrict__ erel, int* __restrict__ cursor,
    int* __restrict__ eidx)
{
    int e = blockIdx.x * 256 + threadIdx.x;
    if (e >= NE) return;
    int d = edst[e];
    int pos = atomicAdd(cursor + d, 1);
    eidx[pos] = esrc[e] | (erel[e] << 17);   // src<2^17, rel<8
}

// ---------------------------------------------------------------------------
// Aggregate: one wave per dst. acc[r][lane*2..] = sum of node_h[src] over
// edges with (rel=r, dst=d), then scale by 1/(1+deg_r). Writes ALL rows
// (zeros included) -> no memset of pre_agg needed.
// ---------------------------------------------------------------------------
__global__ __launch_bounds__(256) void k_agg(
    const float* __restrict__ node_h,
    const int* __restrict__ offs,
    const int* __restrict__ eidx,
    float* __restrict__ pre_agg)    // [NR][NN][FD], normalized
{
    const int t = threadIdx.x;
    const int lane = t & 63;
    const int d = blockIdx.x * 4 + (t >> 6);
    if (d >= NN) return;

    float ax[NR], ay[NR];
    int dg[NR];
#pragma unroll
    for (int r = 0; r < NR; ++r) { ax[r] = 0.f; ay[r] = 0.f; dg[r] = 0; }

    const int beg = offs[d], end = offs[d + 1];
    float2 vcur = make_float2(0.f, 0.f);
    int relcur = 0;
    if (beg < end) {
        int p = eidx[beg];
        relcur = p >> 17;
        vcur = *(const float2*)(node_h + (size_t)(p & 0x1FFFF) * FD + lane * 2);
    }
    for (int j = beg; j < end; ++j) {
        float2 v = vcur;
        int rel = relcur;
        if (j + 1 < end) {   // software pipeline: issue next gather early
            int p = eidx[j + 1];
            relcur = p >> 17;
            vcur = *(const float2*)(node_h + (size_t)(p & 0x1FFFF) * FD + lane * 2);
        }
        switch (rel) {       // wave-uniform branch
            case 0: ax[0] += v.x; ay[0] += v.y; dg[0]++; break;
            case 1: ax[1] += v.x; ay[1] += v.y; dg[1]++; break;
            case 2: ax[2] += v.x; ay[2] += v.y; dg[2]++; break;
            case 3: ax[3] += v.x; ay[3] += v.y; dg[3]++; break;
            case 4: ax[4] += v.x; ay[4] += v.y; dg[4]++; break;
            default: ax[5] += v.x; ay[5] += v.y; dg[5]++; break;
        }
    }
#pragma unroll
    for (int r = 0; r < NR; ++r) {
        float sc = 1.0f / (1.0f + (float)dg[r]);
        *(float2*)(pre_agg + ((size_t)r * NN + d) * FD + lane * 2) =
            make_float2(ax[r] * sc, ay[r] * sc);
    }
}

// ---------------------------------------------------------------------------
// Per-relation GEMM, in place: pre_agg[r,n,:] = pre_agg[r,n,:] @ weight[r]
// (pre_agg already deg-normalized). Tile: 64 rows x 128 cols, K in 2x64.
// ---------------------------------------------------------------------------
__global__ __launch_bounds__(256) void k_rel_gemm(
    float* __restrict__ pre_agg,
    const float* __restrict__ weight)   // [NR][FD][FD] ([k][o])
{
    __shared__ float As[64 * 65];
    __shared__ float Bs[64 * 128];
    const int r  = blockIdx.y;
    const int n0 = blockIdx.x * 64;
    const int t  = threadIdx.x;
    const int tm = t & 15;
    const int tn = t >> 4;

    float acc[4][8];
#pragma unroll
    for (int i = 0; i < 4; ++i)
#pragma unroll
        for (int j = 0; j < 8; ++j) acc[i][j] = 0.f;

    const float* A = pre_agg + (size_t)r * NN * FD;

    for (int kt = 0; kt < 2; ++kt) {
        {
            const float4* w4 = (const float4*)(weight + (size_t)r * FD * FD + kt * 64 * FD);
            float4* b4 = (float4*)Bs;
#pragma unroll
            for (int i = 0; i < 8; ++i) b4[i * 256 + t] = w4[i * 256 + t];
        }
#pragma unroll
        for (int i = 0; i < 4; ++i) {
            int flat = i * 1024 + t * 4;
            int row = flat >> 6;
            int k = flat & 63;
            int n = n0 + row;
            float4 v = make_float4(0.f, 0.f, 0.f, 0.f);
            if (n < NN) v = *(const float4*)(A + (size_t)n * FD + kt * 64 + k);
            float* p = As + row * 65 + k;
            p[0] = v.x; p[1] = v.y; p[2] = v.z; p[3] = v.w;
        }
        __syncthreads();

#pragma unroll 4
        for (int k = 0; k < 64; ++k) {
            float aa[4];
#pragma unroll
            for (int i = 0; i < 4; ++i) aa[i] = As[(4 * tm + i) * 65 + k];
            float4 blo = *(const float4*)(Bs + k * 128 + 8 * tn);
            float4 bhi = *(const float4*)(Bs + k * 128 + 8 * tn + 4);
            float bb[8] = {blo.x, blo.y, blo.z, blo.w, bhi.x, bhi.y, bhi.z, bhi.w};
#pragma unroll
            for (int i = 0; i < 4; ++i)
#pragma unroll
                for (int j = 0; j < 8; ++j) acc[i][j] += aa[i] * bb[j];
        }
        __syncthreads();
    }

    float* C = pre_agg + (size_t)r * NN * FD;
#pragma unroll
    for (int i = 0; i < 4; ++i) {
        int n = n0 + 4 * tm + i;
        if (n < NN) {
            float4* c4 = (float4*)(C + (size_t)n * FD + 8 * tn);
            c4[0] = make_float4(acc[i][0], acc[i][1], acc[i][2], acc[i][3]);
            c4[1] = make_float4(acc[i][4], acc[i][5], acc[i][6], acc[i][7]);
        }
    }
}

// ---------------------------------------------------------------------------
// Attention: per node, softmax over 6 relations (two heads); writes
// v1 over hrs[0][n][:], v2 over hrs[1][n][:] (same wave reads first).
// ---------------------------------------------------------------------------
__global__ __launch_bounds__(256) void k_attn(
    float* __restrict__ hrs,
    const float* __restrict__ att1,
    const float* __restrict__ att2)
{
    const int t = threadIdx.x;
    const int lane = t & 63;
    const int w = t >> 6;
    const int wid = blockIdx.x * 4 + w;
    const int nw = gridDim.x * 4;
    const float a1l = att1[lane], a1h = att1[lane + 64];
    const float a2l = att2[lane], a2h = att2[lane + 64];

    for (int n = wid; n < NN; n += nw) {
        float ol[NR], oh[NR], p1[NR], p2[NR];
#pragma unroll
        for (int r = 0; r < NR; ++r) {
            const float* row = hrs + ((size_t)r * NN + n) * FD;
            ol[r] = row[lane];
            oh[r] = row[lane + 64];
            p1[r] = ol[r] * a1l + oh[r] * a1h;
            p2[r] = ol[r] * a2l + oh[r] * a2h;
        }
#pragma unroll
        for (int off = 32; off > 0; off >>= 1) {
#pragma unroll
            for (int r = 0; r < NR; ++r) {
                p1[r] += __shfl_xor(p1[r], off, 64);
                p2[r] += __shfl_xor(p2[r], off, 64);
            }
        }
        float m1 = p1[0], m2 = p2[0];
#pragma unroll
        for (int r = 1; r < NR; ++r) { m1 = fmaxf(m1, p1[r]); m2 = fmaxf(m2, p2[r]); }
        float s1[NR], s2[NR], d1 = 0.f, d2 = 0.f;
#pragma unroll
        for (int r = 0; r < NR; ++r) {
            s1[r] = __expf(p1[r] - m1); d1 += s1[r];
            s2[r] = __expf(p2[r] - m2); d2 += s2[r];
        }
        d1 = 1.0f / d1; d2 = 1.0f / d2;
        float v1l = 0.f, v1h = 0.f, v2l = 0.f, v2h = 0.f;
#pragma unroll
        for (int r = 0; r < NR; ++r) {
            float w1 = s1[r] * d1, w2 = s2[r] * d2;
            v1l += w1 * ol[r]; v1h += w1 * oh[r];
            v2l += w2 * ol[r]; v2h += w2 * oh[r];
        }
        float* q0 = hrs + (size_t)n * FD;
        float* q1 = hrs + ((size_t)NN + n) * FD;
        q0[lane] = v1l; q0[lane + 64] = v1h;
        q1[lane] = v2l; q1[lane + 64] = v2h;
    }
}

// ---------------------------------------------------------------------------
// Output GEMM: out[n,:] = [V1 V2][n,:] @ Wc^T + 6*bc
// ---------------------------------------------------------------------------
__global__ __launch_bounds__(256) void k_out_gemm(
    const float* __restrict__ V,
    const float* __restrict__ Wc,
    const float* __restrict__ bc,
    float* __restrict__ out)
{
    __shared__ float As[64 * 65];
    __shared__ float Bs[64 * 132];
    const int n0 = blockIdx.x * 64;
    const int t  = threadIdx.x;
    const int tm = t & 15;
    const int tn = t >> 4;

    float acc[4][8];
#pragma unroll
    for (int i = 0; i < 4; ++i)
#pragma unroll
        for (int j = 0; j < 8; ++j) acc[i][j] = 0.f;

    for (int kt = 0; kt < 4; ++kt) {
        const float* Abase = V + (size_t)(kt >> 1) * NN * FD + (kt & 1) * 64;
#pragma unroll
        for (int i = 0; i < 4; ++i) {
            int flat = i * 1024 + t * 4;
            int row = flat >> 6;
            int k = flat & 63;
            int n = n0 + row;
            float4 v = make_float4(0.f, 0.f, 0.f, 0.f);
            if (n < NN) v = *(const float4*)(Abase + (size_t)n * FD + k);
            float* p = As + row * 65 + k;
            p[0] = v.x; p[1] = v.y; p[2] = v.z; p[3] = v.w;
        }
#pragma unroll
        for (int i = 0; i < 8; ++i) {
            int flat4 = i * 256 + t;
            int o = flat4 >> 4;
            int j4 = flat4 & 15;
            float4 v = *(const float4*)(Wc + (size_t)o * 256 + kt * 64 + j4 * 4);
            float* p = Bs + (j4 * 4) * 132 + o;
            p[0] = v.x; p[132] = v.y; p[264] = v.z; p[396] = v.w;
        }
        __syncthreads();

#pragma unroll 4
        for (int k = 0; k < 64; ++k) {
            float aa[4];
#pragma unroll
            for (int i = 0; i < 4; ++i) aa[i] = As[(4 * tm + i) * 65 + k];
            float4 blo = *(const float4*)(Bs + k * 132 + 8 * tn);
            float4 bhi = *(const float4*)(Bs + k * 132 + 8 * tn + 4);
            float bb[8] = {blo.x, blo.y, blo.z, blo.w, bhi.x, bhi.y, bhi.z, bhi.w};
#pragma unroll
            for (int i = 0; i < 4; ++i)
#pragma unroll
                for (int j = 0; j < 8; ++j) acc[i][j] += aa[i] * bb[j];
        }
        __syncthreads();
    }

#pragma unroll
    for (int i = 0; i < 4; ++i) {
        int n = n0 + 4 * tm + i;
        if (n < NN) {
            float* o0 = out + (size_t)n * FD + 8 * tn;
#pragma unroll
            for (int j = 0; j < 8; ++j) o0[j] = acc[i][j] + 6.0f * bc[8 * tn + j];
        }
    }
}

// ---------------------------------------------------------------------------
extern "C" void kernel_launch(void* const* d_in, const int* in_sizes, int n_in,
                              void* d_out, int out_size, void* d_ws, size_t ws_size,
                              hipStream_t stream)
{
    const float* node_h = (const float*)d_in[0];
    const float* weight = (const float*)d_in[1];
    const float* att1   = (const float*)d_in[2];
    const float* att2   = (const float*)d_in[3];
    const float* Wc     = (const float*)d_in[4];
    const float* bc     = (const float*)d_in[5];
    const int* esrc = (const int*)d_in[6];
    const int* edst = (const int*)d_in[7];
    const int* erel = (const int*)d_in[8];
    float* out = (float*)d_out;

    // workspace: pre_agg | offs | cursor(=cnt)   (~154.0 MB, under proven size)
    float* pre_agg = (float*)d_ws;
    int* offs   = (int*)(pre_agg + (size_t)NR * NN * FD);   // NN+1
    int* cursor = offs + (NN + 1);                          // NN (used as cnt first)
    // eidx (3.2 MB) lives in d_out's h-region; consumed before k_out_gemm writes it
    int* eidx = (int*)d_out;

    hipMemsetAsync(cursor, 0, (size_t)NN * sizeof(int), stream);

    k_hist<<<(NE + 255) / 256, 256, 0, stream>>>(edst, cursor);
    k_scan<<<1, 1024, 0, stream>>>(cursor, offs, cursor);
    k_place<<<(NE + 255) / 256, 256, 0, stream>>>(esrc, edst, erel, cursor, eidx);
    k_agg<<<(NN + 3) / 4, 256, 0, stream>>>(node_h, offs, eidx, pre_agg);

    dim3 g1((NN + 63) / 64, NR);
    k_rel_gemm<<<g1, 256, 0, stream>>>(pre_agg, weight);

    k_attn<<<256, 256, 0, stream>>>(pre_agg, att1, att2);

    k_out_gemm<<<(NN + 63) / 64, 256, 0, stream>>>(pre_agg, Wc, bc, out);

    hipMemcpyAsync(out + (size_t)NN * FD, weight,
                   (size_t)NR * FD * FD * sizeof(float),
                   hipMemcpyDeviceToDevice, stream);
}

// Round 3
// 523.745 us; speedup vs baseline: 3.3711x; 1.2745x over previous
//
#include <hip/hip_runtime.h>

#define NN 50000
#define NE 800000
#define NR 6
#define FD 128

typedef __attribute__((ext_vector_type(8))) short bf16x8;
typedef __attribute__((ext_vector_type(4))) float f32x4;

__device__ __forceinline__ unsigned short f2bf(float x) {
    unsigned u = __float_as_uint(x);
    u += 0x7FFFu + ((u >> 16) & 1u);          // round-to-nearest-even
    return (unsigned short)(u >> 16);
}
__device__ __forceinline__ unsigned pack2bf(float lo, float hi) {
    return (unsigned)f2bf(lo) | ((unsigned)f2bf(hi) << 16);
}
__device__ __forceinline__ float bf_lo(unsigned u) { return __uint_as_float(u << 16); }
__device__ __forceinline__ float bf_hi(unsigned u) { return __uint_as_float(u & 0xFFFF0000u); }

// ---------------------------------------------------------------------------
// node_h f32 -> packed bf16x2
// ---------------------------------------------------------------------------
__global__ __launch_bounds__(256) void k_cast(
    const float* __restrict__ node_h, unsigned* __restrict__ nh2)
{
    int i = (blockIdx.x * 256 + threadIdx.x) * 8;   // grid sized exactly
    float4 a = *(const float4*)(node_h + i);
    float4 b = *(const float4*)(node_h + i + 4);
    uint4 o;
    o.x = pack2bf(a.x, a.y); o.y = pack2bf(a.z, a.w);
    o.z = pack2bf(b.x, b.y); o.w = pack2bf(b.z, b.w);
    *(uint4*)(nh2 + i / 2) = o;
}

// ---------------------------------------------------------------------------
// Counting sort by dst
// ---------------------------------------------------------------------------
__global__ __launch_bounds__(256) void k_hist(
    const int* __restrict__ edst, int* __restrict__ cnt)
{
    int e = blockIdx.x * 256 + threadIdx.x;
    if (e < NE) atomicAdd(cnt + edst[e], 1);
}

__global__ __launch_bounds__(1024) void k_scan(
    const int* __restrict__ cnt, int* __restrict__ offs, int* __restrict__ cursor)
{
    __shared__ int partial[1024];
    const int t = threadIdx.x;
    const int per = (NN + 1023) / 1024;
    const int base = t * per;
    int sum = 0;
#pragma unroll 4
    for (int i = 0; i < per; ++i) {
        int idx = base + i;
        if (idx < NN) sum += cnt[idx];
    }
    partial[t] = sum;
    __syncthreads();
    for (int off = 1; off < 1024; off <<= 1) {
        int x = (t >= off) ? partial[t - off] : 0;
        __syncthreads();
        if (t >= off) partial[t] += x;
        __syncthreads();
    }
    int run = partial[t] - sum;
    for (int i = 0; i < per; ++i) {
        int idx = base + i;
        if (idx < NN) {
            int c = cnt[idx];
            offs[idx] = run;
            cursor[idx] = run;
            run += c;
        }
    }
    if (t == 1023) offs[NN] = NE;
}

__global__ __launch_bounds__(256) void k_place(
    const int* __restrict__ esrc, const int* __restrict__ edst,
    const int* __restrict__ erel, int* __restrict__ cursor,
    int* __restrict__ eidx)
{
    int e = blockIdx.x * 256 + threadIdx.x;
    if (e >= NE) return;
    int d = edst[e];
    int pos = atomicAdd(cursor + d, 1);
    eidx[pos] = esrc[e] | (erel[e] << 17);
}

// ---------------------------------------------------------------------------
// w1[r][f] = sum_o weight[r][f][o]*att1[o]; w2 likewise with att2.
// ---------------------------------------------------------------------------
__global__ __launch_bounds__(256) void k_prep_w(
    const float* __restrict__ weight,
    const float* __restrict__ att1, const float* __restrict__ att2,
    float* __restrict__ w1, float* __restrict__ w2)
{
    __shared__ float a1s[FD], a2s[FD];
    const int r = blockIdx.x;
    const int t = threadIdx.x;
    if (t < FD) { a1s[t] = att1[t]; a2s[t] = att2[t]; }
    __syncthreads();
    int f = t & 127;
    const float* av = (t < FD) ? a1s : a2s;
    float* wo = (t < FD) ? w1 : w2;
    const float* Wrow = weight + ((size_t)r * FD + f) * FD;
    float acc = 0.f;
#pragma unroll 8
    for (int o = 0; o < FD; ++o) acc += Wrow[o] * av[o];
    wo[r * FD + f] = acc;
}

// ---------------------------------------------------------------------------
// U_h[r] = W[r] @ Wc_h^T, output packed bf16 in MFMA B-fragment order:
//   element (k=f, n=o) -> Upk[(((h*6+r)*4 + f>>5)*8 + o>>4)*64 + ((f>>3)&3)*16
//                              + (o&15)]*8 + (f&7)
// ---------------------------------------------------------------------------
__global__ __launch_bounds__(256) void k_prep_U(
    const float* __restrict__ weight, const float* __restrict__ Wc,
    short* __restrict__ Upk)
{
    __shared__ float As[64 * 65];
    __shared__ float Bs[64 * 132];
    const int h  = blockIdx.y / NR;
    const int r  = blockIdx.y % NR;
    const int f0 = blockIdx.x * 64;
    const int t  = threadIdx.x;
    const int tm = t & 15, tn = t >> 4;

    float acc[4][8];
#pragma unroll
    for (int i = 0; i < 4; ++i)
#pragma unroll
        for (int j = 0; j < 8; ++j) acc[i][j] = 0.f;

    for (int kt = 0; kt < 2; ++kt) {
#pragma unroll
        for (int i = 0; i < 4; ++i) {
            int flat = i * 1024 + t * 4;
            int row = flat >> 6, k = flat & 63;
            float4 v = *(const float4*)(weight + ((size_t)r * FD + f0 + row) * FD + kt * 64 + k);
            float* p = As + row * 65 + k;
            p[0] = v.x; p[1] = v.y; p[2] = v.z; p[3] = v.w;
        }
#pragma unroll
        for (int i = 0; i < 8; ++i) {
            int flat4 = i * 256 + t;
            int o = flat4 >> 4, j4 = flat4 & 15;
            float4 v = *(const float4*)(Wc + (size_t)o * 256 + h * FD + kt * 64 + j4 * 4);
            float* p = Bs + (j4 * 4) * 132 + o;
            p[0] = v.x; p[132] = v.y; p[264] = v.z; p[396] = v.w;
        }
        __syncthreads();
#pragma unroll 4
        for (int k = 0; k < 64; ++k) {
            float aa[4];
#pragma unroll
            for (int i = 0; i < 4; ++i) aa[i] = As[(4 * tm + i) * 65 + k];
            float4 blo = *(const float4*)(Bs + k * 132 + 8 * tn);
            float4 bhi = *(const float4*)(Bs + k * 132 + 8 * tn + 4);
            float bb[8] = {blo.x, blo.y, blo.z, blo.w, bhi.x, bhi.y, bhi.z, bhi.w};
#pragma unroll
            for (int i = 0; i < 4; ++i)
#pragma unroll
                for (int j = 0; j < 8; ++j) acc[i][j] += aa[i] * bb[j];
        }
        __syncthreads();
    }

#pragma unroll
    for (int i = 0; i < 4; ++i)
#pragma unroll
        for (int j = 0; j < 8; ++j) {
            int f = f0 + 4 * tm + i, o = 8 * tn + j;
            int kstep = f >> 5, g = (f >> 3) & 3, jj = f & 7;
            int nt = o >> 4, ln = g * 16 + (o & 15);
            size_t sidx = ((((size_t)(h * NR + r) * 4 + kstep) * 8 + nt) * 64 + ln) * 8 + jj;
            Upk[sidx] = (short)f2bf(acc[i][j]);
        }
}

// ---------------------------------------------------------------------------
// Aggregate (wave per dst) + per-node softmax logits via w1/w2 + write
// bf16 agg and softmax weights s1,s2.
// ---------------------------------------------------------------------------
__global__ __launch_bounds__(256) void k_agg(
    const unsigned* __restrict__ nh2,   // [NN][64] packed bf16x2
    const int* __restrict__ offs,
    const int* __restrict__ eidx,
    const float* __restrict__ w1v,      // [NR][FD]
    const float* __restrict__ w2v,
    unsigned* __restrict__ aggp,        // [NR][NN][64] packed bf16x2 (normalized)
    float* __restrict__ s1o, float* __restrict__ s2o)   // [NN][NR]
{
    const int t = threadIdx.x;
    const int lane = t & 63;
    const int d = blockIdx.x * 4 + (t >> 6);
    if (d >= NN) return;

    float w1l[NR], w1h[NR], w2l[NR], w2h[NR];
#pragma unroll
    for (int r = 0; r < NR; ++r) {
        float2 a = *(const float2*)(w1v + r * FD + 2 * lane);
        float2 b = *(const float2*)(w2v + r * FD + 2 * lane);
        w1l[r] = a.x; w1h[r] = a.y; w2l[r] = b.x; w2h[r] = b.y;
    }

    float ax[NR], ay[NR];
    int dg[NR];
#pragma unroll
    for (int r = 0; r < NR; ++r) { ax[r] = 0.f; ay[r] = 0.f; dg[r] = 0; }

    const int beg = offs[d], end = offs[d + 1];
    unsigned vcur = 0; int relcur = 0;
    if (beg < end) {
        int p = eidx[beg];
        relcur = p >> 17;
        vcur = nh2[(size_t)(p & 0x1FFFF) * 64 + lane];
    }
    for (int j = beg; j < end; ++j) {
        unsigned v = vcur; int rel = relcur;
        if (j + 1 < end) {
            int p = eidx[j + 1];
            relcur = p >> 17;
            vcur = nh2[(size_t)(p & 0x1FFFF) * 64 + lane];
        }
        float vx = bf_lo(v), vy = bf_hi(v);
        switch (rel) {   // wave-uniform
            case 0: ax[0] += vx; ay[0] += vy; dg[0]++; break;
            case 1: ax[1] += vx; ay[1] += vy; dg[1]++; break;
            case 2: ax[2] += vx; ay[2] += vy; dg[2]++; break;
            case 3: ax[3] += vx; ay[3] += vy; dg[3]++; break;
            case 4: ax[4] += vx; ay[4] += vy; dg[4]++; break;
            default: ax[5] += vx; ay[5] += vy; dg[5]++; break;
        }
    }

    float p1[NR], p2[NR];
#pragma unroll
    for (int r = 0; r < NR; ++r) {
        float sc = 1.0f / (1.0f + (float)dg[r]);
        ax[r] *= sc; ay[r] *= sc;
        p1[r] = ax[r] * w1l[r] + ay[r] * w1h[r];
        p2[r] = ax[r] * w2l[r] + ay[r] * w2h[r];
    }
#pragma unroll
    for (int off = 32; off > 0; off >>= 1)
#pragma unroll
        for (int r = 0; r < NR; ++r) {
            p1[r] += __shfl_xor(p1[r], off, 64);
            p2[r] += __shfl_xor(p2[r], off, 64);
        }

    float m1 = p1[0], m2 = p2[0];
#pragma unroll
    for (int r = 1; r < NR; ++r) { m1 = fmaxf(m1, p1[r]); m2 = fmaxf(m2, p2[r]); }
    float e1[NR], e2[NR], d1 = 0.f, d2 = 0.f;
#pragma unroll
    for (int r = 0; r < NR; ++r) {
        e1[r] = __expf(p1[r] - m1); d1 += e1[r];
        e2[r] = __expf(p2[r] - m2); d2 += e2[r];
    }
    d1 = 1.0f / d1; d2 = 1.0f / d2;

#pragma unroll
    for (int r = 0; r < NR; ++r)
        aggp[((size_t)r * NN + d) * 64 + lane] = pack2bf(ax[r], ay[r]);
    if (lane == 0) {
#pragma unroll
        for (int r = 0; r < NR; ++r) {
            s1o[d * NR + r] = e1[r] * d1;
            s2o[d * NR + r] = e2[r] * d2;
        }
    }
}

// ---------------------------------------------------------------------------
// Fused output GEMM (bf16 MFMA):
//   out[n] = sum_r s1[n,r]*(agg_r[n] @ U1_r) + s2[n,r]*(agg_r[n] @ U2_r) + 6*bc
// Block: 64 nodes x 128 outputs, 4 waves (16 rows each). A staged in LDS
// (XOR-swizzled bf16), B loaded as pre-packed fragments from global (L1/L2).
// Per-relation result scaled by s in FP32 epilogue (s never bf16-rounded).
// ---------------------------------------------------------------------------
__global__ __launch_bounds__(256, 4) void k_fused(
    const unsigned* __restrict__ aggp,  // [NR][NN][64]
    const float* __restrict__ s1, const float* __restrict__ s2,   // [NN][NR]
    const short* __restrict__ Upk,
    const float* __restrict__ bc,
    float* __restrict__ out)
{
    __shared__ short Al[64 * 128];          // bf16 A tile, swizzled
    __shared__ float sl[2 * 64 * NR];       // [h][row][r]
    const int n0 = blockIdx.x * 64;
    const int t = threadIdx.x;
    const int lane = t & 63;
    const int w = t >> 6;

    for (int i = t; i < 2 * 64 * NR; i += 256) {
        int h = i / (64 * NR);
        int rr = i % (64 * NR);
        int row = rr / NR, r = rr % NR;
        int n = n0 + row;
        float v = 0.f;
        if (n < NN) v = (h ? s2 : s1)[(size_t)n * NR + r];
        sl[i] = v;
    }

    f32x4 acc[8];
#pragma unroll
    for (int nt = 0; nt < 8; ++nt) acc[nt] = (f32x4){0.f, 0.f, 0.f, 0.f};

    const int m = w * 16 + (lane & 15);     // A row for this lane's frag
    const int g = lane >> 4;

    for (int r = 0; r < NR; ++r) {
        __syncthreads();   // previous iteration's reads done before overwrite
        {   // stage A tile: 64 rows x 128 bf16
            int row = t >> 2, kq = t & 3;
            int n = n0 + row;
            const unsigned* src = aggp + ((size_t)r * NN + n) * 64 + kq * 16;
#pragma unroll
            for (int c = 0; c < 4; ++c) {
                uint4 v = make_uint4(0, 0, 0, 0);
                if (n < NN) v = *(const uint4*)(src + c * 4);
                int ks = kq * 32 + c * 8;
                int addr = row * 128 + (ks ^ ((row & 7) << 3));
                *(uint4*)&Al[addr] = v;
            }
        }
        __syncthreads();

#pragma unroll
        for (int h = 0; h < 2; ++h) {
            f32x4 ar[8];
#pragma unroll
            for (int nt = 0; nt < 8; ++nt) ar[nt] = (f32x4){0.f, 0.f, 0.f, 0.f};
#pragma unroll
            for (int kstep = 0; kstep < 4; ++kstep) {
                bf16x8 af = *(const bf16x8*)&Al[m * 128 + ((kstep * 32 + g * 8) ^ ((m & 7) << 3))];
                const short* Ub = Upk + (((size_t)(h * NR + r) * 4 + kstep) * 8) * 64 * 8 + lane * 8;
#pragma unroll
                for (int nt = 0; nt < 8; ++nt) {
                    bf16x8 bfr = *(const bf16x8*)(Ub + nt * 64 * 8);
                    ar[nt] = __builtin_amdgcn_mfma_f32_16x16x32_bf16(af, bfr, ar[nt], 0, 0, 0);
                }
            }
            float sv[4];
#pragma unroll
            for (int reg = 0; reg < 4; ++reg)
                sv[reg] = sl[h * 64 * NR + (w * 16 + (lane >> 4) * 4 + reg) * NR + r];
#pragma unroll
            for (int nt = 0; nt < 8; ++nt)
#pragma unroll
                for (int reg = 0; reg < 4; ++reg)
                    acc[nt][reg] += sv[reg] * ar[nt][reg];
        }
    }

    const int rowbase = n0 + w * 16 + (lane >> 4) * 4;
    const int col0 = lane & 15;
#pragma unroll
    for (int nt = 0; nt < 8; ++nt) {
        int col = nt * 16 + col0;
        float b6 = 6.0f * bc[col];
#pragma unroll
        for (int reg = 0; reg < 4; ++reg) {
            int n = rowbase + reg;
            if (n < NN) out[(size_t)n * FD + col] = acc[nt][reg] + b6;
        }
    }
}

// ---------------------------------------------------------------------------
extern "C" void kernel_launch(void* const* d_in, const int* in_sizes, int n_in,
                              void* d_out, int out_size, void* d_ws, size_t ws_size,
                              hipStream_t stream)
{
    const float* node_h = (const float*)d_in[0];
    const float* weight = (const float*)d_in[1];
    const float* att1   = (const float*)d_in[2];
    const float* att2   = (const float*)d_in[3];
    const float* Wc     = (const float*)d_in[4];
    const float* bc     = (const float*)d_in[5];
    const int* esrc = (const int*)d_in[6];
    const int* edst = (const int*)d_in[7];
    const int* erel = (const int*)d_in[8];
    float* out = (float*)d_out;

    char* wsp = (char*)d_ws;
    auto alloc = [&](size_t bytes) {
        char* p = wsp;
        wsp += (bytes + 255) & ~(size_t)255;
        return p;
    };
    unsigned* aggp = (unsigned*)alloc((size_t)NR * NN * 64 * 4);
    unsigned* nh2  = (unsigned*)alloc((size_t)NN * 64 * 4);
    short* Upk     = (short*)alloc((size_t)2 * NR * FD * FD * 2);
    float* w1      = (float*)alloc(NR * FD * 4);
    float* w2      = (float*)alloc(NR * FD * 4);
    float* s1      = (float*)alloc((size_t)NN * NR * 4);
    float* s2      = (float*)alloc((size_t)NN * NR * 4);
    int* offs      = (int*)alloc((NN + 1) * 4);
    int* cursor    = (int*)alloc(NN * 4);
    int* eidx      = (int*)d_out;   // scratch in h-region; consumed by k_agg

    hipMemsetAsync(cursor, 0, (size_t)NN * sizeof(int), stream);

    k_hist<<<(NE + 255) / 256, 256, 0, stream>>>(edst, cursor);
    k_scan<<<1, 1024, 0, stream>>>(cursor, offs, cursor);
    k_place<<<(NE + 255) / 256, 256, 0, stream>>>(esrc, edst, erel, cursor, eidx);

    k_cast<<<(NN * FD / 8 + 255) / 256, 256, 0, stream>>>(node_h, nh2);
    k_prep_w<<<NR, 256, 0, stream>>>(weight, att1, att2, w1, w2);
    k_prep_U<<<dim3(2, 2 * NR), 256, 0, stream>>>(weight, Wc, Upk);

    k_agg<<<(NN + 3) / 4, 256, 0, stream>>>(nh2, offs, eidx, w1, w2, aggp, s1, s2);

    k_fused<<<(NN + 63) / 64, 256, 0, stream>>>(aggp, s1, s2, Upk, bc, out);

    hipMemcpyAsync(out + (size_t)NN * FD, weight,
                   (size_t)NR * FD * FD * sizeof(float),
                   hipMemcpyDeviceToDevice, stream);
}

// Round 4
// 390.231 us; speedup vs baseline: 4.5245x; 1.3421x over previous
//
#include <hip/hip_runtime.h>

#define NN 50000
#define NE 800000
#define NR 6
#define FD 128
#define NS (NN * NR)              // segment count (dst,rel)
#define MB ((NS + 1023) / 1024)   // scan blocks (293)

typedef __attribute__((ext_vector_type(8))) short bf16x8;
typedef __attribute__((ext_vector_type(4))) float f32x4;

__device__ __forceinline__ unsigned short f2bf(float x) {
    unsigned u = __float_as_uint(x);
    u += 0x7FFFu + ((u >> 16) & 1u);          // round-to-nearest-even
    return (unsigned short)(u >> 16);
}
__device__ __forceinline__ unsigned pack2bf(float lo, float hi) {
    return (unsigned)f2bf(lo) | ((unsigned)f2bf(hi) << 16);
}
__device__ __forceinline__ float bf_lo(unsigned u) { return __uint_as_float(u << 16); }
__device__ __forceinline__ float bf_hi(unsigned u) { return __uint_as_float(u & 0xFFFF0000u); }

// ---------------------------------------------------------------------------
// node_h f32 -> packed bf16x2
// ---------------------------------------------------------------------------
__global__ __launch_bounds__(256) void k_cast(
    const float* __restrict__ node_h, unsigned* __restrict__ nh2)
{
    int i = (blockIdx.x * 256 + threadIdx.x) * 8;   // grid sized exactly
    float4 a = *(const float4*)(node_h + i);
    float4 b = *(const float4*)(node_h + i + 4);
    uint4 o;
    o.x = pack2bf(a.x, a.y); o.y = pack2bf(a.z, a.w);
    o.z = pack2bf(b.x, b.y); o.w = pack2bf(b.z, b.w);
    *(uint4*)(nh2 + i / 2) = o;
}

// ---------------------------------------------------------------------------
// Counting sort by seg = dst*NR + rel
// ---------------------------------------------------------------------------
__global__ __launch_bounds__(256) void k_hist(
    const int* __restrict__ edst, const int* __restrict__ erel,
    int* __restrict__ cnt)
{
    int e = blockIdx.x * 256 + threadIdx.x;
    if (e < NE) atomicAdd(cnt + edst[e] * NR + erel[e], 1);
}

// Stage 1: per-block (1024 elems) sums. Coalesced int4.
__global__ __launch_bounds__(256) void k_bsum(
    const int* __restrict__ cnt, int* __restrict__ bsum)
{
    __shared__ int red[256];
    const int b = blockIdx.x, t = threadIdx.x;
    int idx0 = b * 1024 + t * 4;
    int4 c = *(const int4*)(cnt + idx0);   // cnt is padded; mask below
    int s = 0;
    if (idx0 + 0 < NS) s += c.x;
    if (idx0 + 1 < NS) s += c.y;
    if (idx0 + 2 < NS) s += c.z;
    if (idx0 + 3 < NS) s += c.w;
    red[t] = s;
    __syncthreads();
    for (int off = 128; off > 0; off >>= 1) {
        if (t < off) red[t] += red[t + off];
        __syncthreads();
    }
    if (t == 0) bsum[b] = red[0];
}

// Stage 2: one block scans the MB block sums -> exclusive prefixes.
__global__ __launch_bounds__(512) void k_scanb(
    const int* __restrict__ bsum, int* __restrict__ bpre)
{
    __shared__ int s[512];
    const int t = threadIdx.x;
    int v = (t < MB) ? bsum[t] : 0;
    s[t] = v;
    __syncthreads();
    for (int off = 1; off < 512; off <<= 1) {
        int x = (t >= off) ? s[t - off] : 0;
        __syncthreads();
        if (t >= off) s[t] += x;
        __syncthreads();
    }
    bpre[t] = s[t] - v;   // exclusive
}

// Stage 3: per-block exclusive scan + bpre, writes offs and cursor. Coalesced.
__global__ __launch_bounds__(256) void k_scan3(
    const int* __restrict__ cnt, const int* __restrict__ bpre,
    int* __restrict__ offs, int* __restrict__ cursor)
{
    __shared__ int partial[256];
    const int b = blockIdx.x, t = threadIdx.x;
    int idx0 = b * 1024 + t * 4;
    int4 c = *(const int4*)(cnt + idx0);
    if (idx0 + 0 >= NS) c.x = 0;
    if (idx0 + 1 >= NS) c.y = 0;
    if (idx0 + 2 >= NS) c.z = 0;
    if (idx0 + 3 >= NS) c.w = 0;
    int tsum = c.x + c.y + c.z + c.w;
    partial[t] = tsum;
    __syncthreads();
    for (int off = 1; off < 256; off <<= 1) {
        int x = (t >= off) ? partial[t - off] : 0;
        __syncthreads();
        if (t >= off) partial[t] += x;
        __syncthreads();
    }
    int base = bpre[b] + partial[t] - tsum;
    int4 o;
    o.x = base;
    o.y = base + c.x;
    o.z = base + c.x + c.y;
    o.w = base + c.x + c.y + c.z;
    if (idx0 + 3 < NS) {
        *(int4*)(offs + idx0) = o;
        *(int4*)(cursor + idx0) = o;
    } else {
        int v[4] = {o.x, o.y, o.z, o.w};
        for (int k = 0; k < 4; ++k)
            if (idx0 + k < NS) { offs[idx0 + k] = v[k]; cursor[idx0 + k] = v[k]; }
    }
    if (b == 0 && t == 0) offs[NS] = NE;
}

__global__ __launch_bounds__(256) void k_place(
    const int* __restrict__ esrc, const int* __restrict__ edst,
    const int* __restrict__ erel, int* __restrict__ cursor,
    int* __restrict__ eidx)
{
    int e = blockIdx.x * 256 + threadIdx.x;
    if (e >= NE) return;
    int seg = edst[e] * NR + erel[e];
    int pos = atomicAdd(cursor + seg, 1);
    eidx[pos] = esrc[e];
}

// ---------------------------------------------------------------------------
// w1[r][f] = sum_o weight[r][f][o]*att1[o]; w2 likewise with att2.
// ---------------------------------------------------------------------------
__global__ __launch_bounds__(256) void k_prep_w(
    const float* __restrict__ weight,
    const float* __restrict__ att1, const float* __restrict__ att2,
    float* __restrict__ w1, float* __restrict__ w2)
{
    __shared__ float a1s[FD], a2s[FD];
    const int r = blockIdx.x;
    const int t = threadIdx.x;
    if (t < FD) { a1s[t] = att1[t]; a2s[t] = att2[t]; }
    __syncthreads();
    int f = t & 127;
    const float* av = (t < FD) ? a1s : a2s;
    float* wo = (t < FD) ? w1 : w2;
    const float* Wrow = weight + ((size_t)r * FD + f) * FD;
    float acc = 0.f;
#pragma unroll 8
    for (int o = 0; o < FD; ++o) acc += Wrow[o] * av[o];
    wo[r * FD + f] = acc;
}

// ---------------------------------------------------------------------------
// U_h[r] = W[r] @ Wc_h^T, packed bf16 in MFMA B-fragment order.
// ---------------------------------------------------------------------------
__global__ __launch_bounds__(256) void k_prep_U(
    const float* __restrict__ weight, const float* __restrict__ Wc,
    short* __restrict__ Upk)
{
    __shared__ float As[64 * 65];
    __shared__ float Bs[64 * 132];
    const int h  = blockIdx.y / NR;
    const int r  = blockIdx.y % NR;
    const int f0 = blockIdx.x * 64;
    const int t  = threadIdx.x;
    const int tm = t & 15, tn = t >> 4;

    float acc[4][8];
#pragma unroll
    for (int i = 0; i < 4; ++i)
#pragma unroll
        for (int j = 0; j < 8; ++j) acc[i][j] = 0.f;

    for (int kt = 0; kt < 2; ++kt) {
#pragma unroll
        for (int i = 0; i < 4; ++i) {
            int flat = i * 1024 + t * 4;
            int row = flat >> 6, k = flat & 63;
            float4 v = *(const float4*)(weight + ((size_t)r * FD + f0 + row) * FD + kt * 64 + k);
            float* p = As + row * 65 + k;
            p[0] = v.x; p[1] = v.y; p[2] = v.z; p[3] = v.w;
        }
#pragma unroll
        for (int i = 0; i < 8; ++i) {
            int flat4 = i * 256 + t;
            int o = flat4 >> 4, j4 = flat4 & 15;
            float4 v = *(const float4*)(Wc + (size_t)o * 256 + h * FD + kt * 64 + j4 * 4);
            float* p = Bs + (j4 * 4) * 132 + o;
            p[0] = v.x; p[132] = v.y; p[264] = v.z; p[396] = v.w;
        }
        __syncthreads();
#pragma unroll 4
        for (int k = 0; k < 64; ++k) {
            float aa[4];
#pragma unroll
            for (int i = 0; i < 4; ++i) aa[i] = As[(4 * tm + i) * 65 + k];
            float4 blo = *(const float4*)(Bs + k * 132 + 8 * tn);
            float4 bhi = *(const float4*)(Bs + k * 132 + 8 * tn + 4);
            float bb[8] = {blo.x, blo.y, blo.z, blo.w, bhi.x, bhi.y, bhi.z, bhi.w};
#pragma unroll
            for (int i = 0; i < 4; ++i)
#pragma unroll
                for (int j = 0; j < 8; ++j) acc[i][j] += aa[i] * bb[j];
        }
        __syncthreads();
    }

#pragma unroll
    for (int i = 0; i < 4; ++i)
#pragma unroll
        for (int j = 0; j < 8; ++j) {
            int f = f0 + 4 * tm + i, o = 8 * tn + j;
            int kstep = f >> 5, g = (f >> 3) & 3, jj = f & 7;
            int nt = o >> 4, ln = g * 16 + (o & 15);
            size_t sidx = ((((size_t)(h * NR + r) * 4 + kstep) * 8 + nt) * 64 + ln) * 8 + jj;
            Upk[sidx] = (short)f2bf(acc[i][j]);
        }
}

// ---------------------------------------------------------------------------
// Aggregate: wave per dst; edges pre-sorted by (dst,rel) so each relation is
// a contiguous segment — no per-edge rel decode, degree = segment length.
// Emits bf16 normalized agg rows + softmax weights s1,s2.
// ---------------------------------------------------------------------------
__global__ __launch_bounds__(256) void k_agg(
    const unsigned* __restrict__ nh2,   // [NN][64] packed bf16x2
    const int* __restrict__ offs,       // [NS+1]
    const int* __restrict__ eidx,       // [NE] src
    const float* __restrict__ w1v, const float* __restrict__ w2v,
    unsigned* __restrict__ aggp,        // [NR][NN][64]
    float* __restrict__ s1o, float* __restrict__ s2o)
{
    const int t = threadIdx.x;
    const int lane = t & 63;
    const int d = blockIdx.x * 4 + (t >> 6);
    if (d >= NN) return;

    float w1l[NR], w1h[NR], w2l[NR], w2h[NR];
#pragma unroll
    for (int r = 0; r < NR; ++r) {
        float2 a = *(const float2*)(w1v + r * FD + 2 * lane);
        float2 b = *(const float2*)(w2v + r * FD + 2 * lane);
        w1l[r] = a.x; w1h[r] = a.y; w2l[r] = b.x; w2h[r] = b.y;
    }

    int bnd[NR + 1];
#pragma unroll
    for (int i = 0; i <= NR; ++i) bnd[i] = offs[d * NR + i];

    float p1[NR], p2[NR];
#pragma unroll
    for (int r = 0; r < NR; ++r) {
        const int beg = bnd[r], end = bnd[r + 1];
        float ax = 0.f, ay = 0.f;
        unsigned vcur = 0;
        if (beg < end) vcur = nh2[(size_t)eidx[beg] * 64 + lane];
        for (int j = beg; j < end; ++j) {
            unsigned v = vcur;
            if (j + 1 < end) vcur = nh2[(size_t)eidx[j + 1] * 64 + lane];
            ax += bf_lo(v); ay += bf_hi(v);
        }
        float sc = 1.0f / (1.0f + (float)(end - beg));
        ax *= sc; ay *= sc;
        aggp[((size_t)r * NN + d) * 64 + lane] = pack2bf(ax, ay);
        p1[r] = ax * w1l[r] + ay * w1h[r];
        p2[r] = ax * w2l[r] + ay * w2h[r];
    }

#pragma unroll
    for (int off = 32; off > 0; off >>= 1)
#pragma unroll
        for (int r = 0; r < NR; ++r) {
            p1[r] += __shfl_xor(p1[r], off, 64);
            p2[r] += __shfl_xor(p2[r], off, 64);
        }

    float m1 = p1[0], m2 = p2[0];
#pragma unroll
    for (int r = 1; r < NR; ++r) { m1 = fmaxf(m1, p1[r]); m2 = fmaxf(m2, p2[r]); }
    float e1[NR], e2[NR], d1 = 0.f, d2 = 0.f;
#pragma unroll
    for (int r = 0; r < NR; ++r) {
        e1[r] = __expf(p1[r] - m1); d1 += e1[r];
        e2[r] = __expf(p2[r] - m2); d2 += e2[r];
    }
    d1 = 1.0f / d1; d2 = 1.0f / d2;
    if (lane == 0) {
#pragma unroll
        for (int r = 0; r < NR; ++r) {
            s1o[d * NR + r] = e1[r] * d1;
            s2o[d * NR + r] = e2[r] * d2;
        }
    }
}

// ---------------------------------------------------------------------------
// Fused output GEMM (bf16 MFMA):
//   out[n] = sum_r s1[n,r]*(agg_r[n] @ U1_r) + s2[n,r]*(agg_r[n] @ U2_r) + 6*bc
// ---------------------------------------------------------------------------
__global__ __launch_bounds__(256, 4) void k_fused(
    const unsigned* __restrict__ aggp,
    const float* __restrict__ s1, const float* __restrict__ s2,
    const short* __restrict__ Upk,
    const float* __restrict__ bc,
    float* __restrict__ out)
{
    __shared__ short Al[64 * 128];
    __shared__ float sl[2 * 64 * NR];
    const int n0 = blockIdx.x * 64;
    const int t = threadIdx.x;
    const int lane = t & 63;
    const int w = t >> 6;

    for (int i = t; i < 2 * 64 * NR; i += 256) {
        int h = i / (64 * NR);
        int rr = i % (64 * NR);
        int row = rr / NR, r = rr % NR;
        int n = n0 + row;
        float v = 0.f;
        if (n < NN) v = (h ? s2 : s1)[(size_t)n * NR + r];
        sl[i] = v;
    }

    f32x4 acc[8];
#pragma unroll
    for (int nt = 0; nt < 8; ++nt) acc[nt] = (f32x4){0.f, 0.f, 0.f, 0.f};

    const int m = w * 16 + (lane & 15);
    const int g = lane >> 4;

    for (int r = 0; r < NR; ++r) {
        __syncthreads();
        {
            int row = t >> 2, kq = t & 3;
            int n = n0 + row;
            const unsigned* src = aggp + ((size_t)r * NN + n) * 64 + kq * 16;
#pragma unroll
            for (int c = 0; c < 4; ++c) {
                uint4 v = make_uint4(0, 0, 0, 0);
                if (n < NN) v = *(const uint4*)(src + c * 4);
                int ks = kq * 32 + c * 8;
                int addr = row * 128 + (ks ^ ((row & 7) << 3));
                *(uint4*)&Al[addr] = v;
            }
        }
        __syncthreads();

#pragma unroll
        for (int h = 0; h < 2; ++h) {
            f32x4 ar[8];
#pragma unroll
            for (int nt = 0; nt < 8; ++nt) ar[nt] = (f32x4){0.f, 0.f, 0.f, 0.f};
#pragma unroll
            for (int kstep = 0; kstep < 4; ++kstep) {
                bf16x8 af = *(const bf16x8*)&Al[m * 128 + ((kstep * 32 + g * 8) ^ ((m & 7) << 3))];
                const short* Ub = Upk + (((size_t)(h * NR + r) * 4 + kstep) * 8) * 64 * 8 + lane * 8;
#pragma unroll
                for (int nt = 0; nt < 8; ++nt) {
                    bf16x8 bfr = *(const bf16x8*)(Ub + nt * 64 * 8);
                    ar[nt] = __builtin_amdgcn_mfma_f32_16x16x32_bf16(af, bfr, ar[nt], 0, 0, 0);
                }
            }
            float sv[4];
#pragma unroll
            for (int reg = 0; reg < 4; ++reg)
                sv[reg] = sl[h * 64 * NR + (w * 16 + (lane >> 4) * 4 + reg) * NR + r];
#pragma unroll
            for (int nt = 0; nt < 8; ++nt)
#pragma unroll
                for (int reg = 0; reg < 4; ++reg)
                    acc[nt][reg] += sv[reg] * ar[nt][reg];
        }
    }

    const int rowbase = n0 + w * 16 + (lane >> 4) * 4;
    const int col0 = lane & 15;
#pragma unroll
    for (int nt = 0; nt < 8; ++nt) {
        int col = nt * 16 + col0;
        float b6 = 6.0f * bc[col];
#pragma unroll
        for (int reg = 0; reg < 4; ++reg) {
            int n = rowbase + reg;
            if (n < NN) out[(size_t)n * FD + col] = acc[nt][reg] + b6;
        }
    }
}

// ---------------------------------------------------------------------------
extern "C" void kernel_launch(void* const* d_in, const int* in_sizes, int n_in,
                              void* d_out, int out_size, void* d_ws, size_t ws_size,
                              hipStream_t stream)
{
    const float* node_h = (const float*)d_in[0];
    const float* weight = (const float*)d_in[1];
    const float* att1   = (const float*)d_in[2];
    const float* att2   = (const float*)d_in[3];
    const float* Wc     = (const float*)d_in[4];
    const float* bc     = (const float*)d_in[5];
    const int* esrc = (const int*)d_in[6];
    const int* edst = (const int*)d_in[7];
    const int* erel = (const int*)d_in[8];
    float* out = (float*)d_out;

    char* wsp = (char*)d_ws;
    auto alloc = [&](size_t bytes) {
        char* p = wsp;
        wsp += (bytes + 255) & ~(size_t)255;
        return p;
    };
    unsigned* aggp = (unsigned*)alloc((size_t)NR * NN * 64 * 4);
    unsigned* nh2  = (unsigned*)alloc((size_t)NN * 64 * 4);
    short* Upk     = (short*)alloc((size_t)2 * NR * FD * FD * 2);
    float* w1      = (float*)alloc(NR * FD * 4);
    float* w2      = (float*)alloc(NR * FD * 4);
    float* s1      = (float*)alloc((size_t)NN * NR * 4);
    float* s2      = (float*)alloc((size_t)NN * NR * 4);
    int* offs      = (int*)alloc((size_t)(NS + 1 + 64) * 4);
    int* cursor    = (int*)alloc((size_t)(NS + 2048) * 4);  // also 'cnt'; padded for int4 tails
    int* bsum      = (int*)alloc(512 * 4);
    int* bpre      = (int*)alloc(512 * 4);
    int* eidx      = (int*)d_out;   // scratch in out's h-region; consumed by k_agg

    hipMemsetAsync(cursor, 0, (size_t)NS * sizeof(int), stream);

    k_hist<<<(NE + 255) / 256, 256, 0, stream>>>(edst, erel, cursor);
    k_bsum<<<MB, 256, 0, stream>>>(cursor, bsum);
    k_scanb<<<1, 512, 0, stream>>>(bsum, bpre);
    k_scan3<<<MB, 256, 0, stream>>>(cursor, bpre, offs, cursor);
    k_place<<<(NE + 255) / 256, 256, 0, stream>>>(esrc, edst, erel, cursor, eidx);

    k_cast<<<(NN * FD / 8 + 255) / 256, 256, 0, stream>>>(node_h, nh2);
    k_prep_w<<<NR, 256, 0, stream>>>(weight, att1, att2, w1, w2);
    k_prep_U<<<dim3(2, 2 * NR), 256, 0, stream>>>(weight, Wc, Upk);

    k_agg<<<(NN + 3) / 4, 256, 0, stream>>>(nh2, offs, eidx, w1, w2, aggp, s1, s2);

    k_fused<<<(NN + 63) / 64, 256, 0, stream>>>(aggp, s1, s2, Upk, bc, out);

    hipMemcpyAsync(out + (size_t)NN * FD, weight,
                   (size_t)NR * FD * FD * sizeof(float),
                   hipMemcpyDeviceToDevice, stream);
}

// Round 5
// 355.086 us; speedup vs baseline: 4.9723x; 1.0990x over previous
//
#include <hip/hip_runtime.h>

#define NN 50000
#define NE 800000
#define NR 6
#define FD 128
#define NS (NN * NR)              // segment count (dst,rel)
#define MB ((NS + 1023) / 1024)   // scan blocks (293)

typedef __attribute__((ext_vector_type(8))) short bf16x8;
typedef __attribute__((ext_vector_type(4))) float f32x4;

__device__ __forceinline__ unsigned short f2bf(float x) {
    unsigned u = __float_as_uint(x);
    u += 0x7FFFu + ((u >> 16) & 1u);          // round-to-nearest-even
    return (unsigned short)(u >> 16);
}
__device__ __forceinline__ unsigned pack2bf(float lo, float hi) {
    return (unsigned)f2bf(lo) | ((unsigned)f2bf(hi) << 16);
}
__device__ __forceinline__ float bf_lo(unsigned u) { return __uint_as_float(u << 16); }
__device__ __forceinline__ float bf_hi(unsigned u) { return __uint_as_float(u & 0xFFFF0000u); }

// ---------------------------------------------------------------------------
// node_h f32 -> packed bf16x2
// ---------------------------------------------------------------------------
__global__ __launch_bounds__(256) void k_cast(
    const float* __restrict__ node_h, unsigned* __restrict__ nh2)
{
    int i = (blockIdx.x * 256 + threadIdx.x) * 8;   // grid sized exactly
    float4 a = *(const float4*)(node_h + i);
    float4 b = *(const float4*)(node_h + i + 4);
    uint4 o;
    o.x = pack2bf(a.x, a.y); o.y = pack2bf(a.z, a.w);
    o.z = pack2bf(b.x, b.y); o.w = pack2bf(b.z, b.w);
    *(uint4*)(nh2 + i / 2) = o;
}

// ---------------------------------------------------------------------------
// Counting sort by seg = dst*NR + rel
// ---------------------------------------------------------------------------
__global__ __launch_bounds__(256) void k_hist(
    const int* __restrict__ edst, const int* __restrict__ erel,
    int* __restrict__ cnt)
{
    int e = blockIdx.x * 256 + threadIdx.x;
    if (e < NE) atomicAdd(cnt + edst[e] * NR + erel[e], 1);
}

// Stage 1: per-block (1024 elems) sums. Coalesced int4.
__global__ __launch_bounds__(256) void k_bsum(
    const int* __restrict__ cnt, int* __restrict__ bsum)
{
    __shared__ int red[256];
    const int b = blockIdx.x, t = threadIdx.x;
    int idx0 = b * 1024 + t * 4;
    int4 c = *(const int4*)(cnt + idx0);   // cnt is padded; mask below
    int s = 0;
    if (idx0 + 0 < NS) s += c.x;
    if (idx0 + 1 < NS) s += c.y;
    if (idx0 + 2 < NS) s += c.z;
    if (idx0 + 3 < NS) s += c.w;
    red[t] = s;
    __syncthreads();
    for (int off = 128; off > 0; off >>= 1) {
        if (t < off) red[t] += red[t + off];
        __syncthreads();
    }
    if (t == 0) bsum[b] = red[0];
}

// Stage 2: one block scans the MB block sums -> exclusive prefixes.
__global__ __launch_bounds__(512) void k_scanb(
    const int* __restrict__ bsum, int* __restrict__ bpre)
{
    __shared__ int s[512];
    const int t = threadIdx.x;
    int v = (t < MB) ? bsum[t] : 0;
    s[t] = v;
    __syncthreads();
    for (int off = 1; off < 512; off <<= 1) {
        int x = (t >= off) ? s[t - off] : 0;
        __syncthreads();
        if (t >= off) s[t] += x;
        __syncthreads();
    }
    bpre[t] = s[t] - v;   // exclusive
}

// Stage 3: per-block exclusive scan + bpre, writes offs and cursor. Coalesced.
__global__ __launch_bounds__(256) void k_scan3(
    const int* __restrict__ cnt, const int* __restrict__ bpre,
    int* __restrict__ offs, int* __restrict__ cursor)
{
    __shared__ int partial[256];
    const int b = blockIdx.x, t = threadIdx.x;
    int idx0 = b * 1024 + t * 4;
    int4 c = *(const int4*)(cnt + idx0);
    if (idx0 + 0 >= NS) c.x = 0;
    if (idx0 + 1 >= NS) c.y = 0;
    if (idx0 + 2 >= NS) c.z = 0;
    if (idx0 + 3 >= NS) c.w = 0;
    int tsum = c.x + c.y + c.z + c.w;
    partial[t] = tsum;
    __syncthreads();
    for (int off = 1; off < 256; off <<= 1) {
        int x = (t >= off) ? partial[t - off] : 0;
        __syncthreads();
        if (t >= off) partial[t] += x;
        __syncthreads();
    }
    int base = bpre[b] + partial[t] - tsum;
    int4 o;
    o.x = base;
    o.y = base + c.x;
    o.z = base + c.x + c.y;
    o.w = base + c.x + c.y + c.z;
    if (idx0 + 3 < NS) {
        *(int4*)(offs + idx0) = o;
        *(int4*)(cursor + idx0) = o;
    } else {
        int v[4] = {o.x, o.y, o.z, o.w};
        for (int k = 0; k < 4; ++k)
            if (idx0 + k < NS) { offs[idx0 + k] = v[k]; cursor[idx0 + k] = v[k]; }
    }
    if (b == 0 && t == 0) offs[NS] = NE;
}

__global__ __launch_bounds__(256) void k_place(
    const int* __restrict__ esrc, const int* __restrict__ edst,
    const int* __restrict__ erel, int* __restrict__ cursor,
    int* __restrict__ eidx)
{
    int e = blockIdx.x * 256 + threadIdx.x;
    if (e >= NE) return;
    int seg = edst[e] * NR + erel[e];
    int pos = atomicAdd(cursor + seg, 1);
    eidx[pos] = esrc[e];
}

// ---------------------------------------------------------------------------
// w1[r][f] = sum_o weight[r][f][o]*att1[o]; w2 likewise with att2.
// ---------------------------------------------------------------------------
__global__ __launch_bounds__(256) void k_prep_w(
    const float* __restrict__ weight,
    const float* __restrict__ att1, const float* __restrict__ att2,
    float* __restrict__ w1, float* __restrict__ w2)
{
    __shared__ float a1s[FD], a2s[FD];
    const int r = blockIdx.x;
    const int t = threadIdx.x;
    if (t < FD) { a1s[t] = att1[t]; a2s[t] = att2[t]; }
    __syncthreads();
    int f = t & 127;
    const float* av = (t < FD) ? a1s : a2s;
    float* wo = (t < FD) ? w1 : w2;
    const float* Wrow = weight + ((size_t)r * FD + f) * FD;
    float acc = 0.f;
#pragma unroll 8
    for (int o = 0; o < FD; ++o) acc += Wrow[o] * av[o];
    wo[r * FD + f] = acc;
}

// ---------------------------------------------------------------------------
// U_h[r] = W[r] @ Wc_h^T, packed bf16 in MFMA B-fragment order.
// ---------------------------------------------------------------------------
__global__ __launch_bounds__(256) void k_prep_U(
    const float* __restrict__ weight, const float* __restrict__ Wc,
    short* __restrict__ Upk)
{
    __shared__ float As[64 * 65];
    __shared__ float Bs[64 * 132];
    const int h  = blockIdx.y / NR;
    const int r  = blockIdx.y % NR;
    const int f0 = blockIdx.x * 64;
    const int t  = threadIdx.x;
    const int tm = t & 15, tn = t >> 4;

    float acc[4][8];
#pragma unroll
    for (int i = 0; i < 4; ++i)
#pragma unroll
        for (int j = 0; j < 8; ++j) acc[i][j] = 0.f;

    for (int kt = 0; kt < 2; ++kt) {
#pragma unroll
        for (int i = 0; i < 4; ++i) {
            int flat = i * 1024 + t * 4;
            int row = flat >> 6, k = flat & 63;
            float4 v = *(const float4*)(weight + ((size_t)r * FD + f0 + row) * FD + kt * 64 + k);
            float* p = As + row * 65 + k;
            p[0] = v.x; p[1] = v.y; p[2] = v.z; p[3] = v.w;
        }
#pragma unroll
        for (int i = 0; i < 8; ++i) {
            int flat4 = i * 256 + t;
            int o = flat4 >> 4, j4 = flat4 & 15;
            float4 v = *(const float4*)(Wc + (size_t)o * 256 + h * FD + kt * 64 + j4 * 4);
            float* p = Bs + (j4 * 4) * 132 + o;
            p[0] = v.x; p[132] = v.y; p[264] = v.z; p[396] = v.w;
        }
        __syncthreads();
#pragma unroll 4
        for (int k = 0; k < 64; ++k) {
            float aa[4];
#pragma unroll
            for (int i = 0; i < 4; ++i) aa[i] = As[(4 * tm + i) * 65 + k];
            float4 blo = *(const float4*)(Bs + k * 132 + 8 * tn);
            float4 bhi = *(const float4*)(Bs + k * 132 + 8 * tn + 4);
            float bb[8] = {blo.x, blo.y, blo.z, blo.w, bhi.x, bhi.y, bhi.z, bhi.w};
#pragma unroll
            for (int i = 0; i < 4; ++i)
#pragma unroll
                for (int j = 0; j < 8; ++j) acc[i][j] += aa[i] * bb[j];
        }
        __syncthreads();
    }

#pragma unroll
    for (int i = 0; i < 4; ++i)
#pragma unroll
        for (int j = 0; j < 8; ++j) {
            int f = f0 + 4 * tm + i, o = 8 * tn + j;
            int kstep = f >> 5, g = (f >> 3) & 3, jj = f & 7;
            int nt = o >> 4, ln = g * 16 + (o & 15);
            size_t sidx = ((((size_t)(h * NR + r) * 4 + kstep) * 8 + nt) * 64 + ln) * 8 + jj;
            Upk[sidx] = (short)f2bf(acc[i][j]);
        }
}

// ---------------------------------------------------------------------------
// Aggregate v2: one wave per dst; 4 groups of 16 lanes, each group owns one
// relation segment (pass 0: r=grp, pass 1: r=4+grp). Each lane covers 8
// features (uint4 = 16B load). No cross-group reduce needed; logits via
// 4-step in-group shuffles; softmax replicated wave-wide.
// ---------------------------------------------------------------------------
__global__ __launch_bounds__(256) void k_agg(
    const unsigned* __restrict__ nh2,   // [NN][64] packed bf16x2
    const int* __restrict__ offs,       // [NS+1]
    const int* __restrict__ eidx,       // [NE] src
    const float* __restrict__ w1v, const float* __restrict__ w2v,
    unsigned* __restrict__ aggp,        // [NR][NN][64]
    float* __restrict__ s1o, float* __restrict__ s2o)
{
    const int t = threadIdx.x;
    const int lane = t & 63;
    const int grp = lane >> 4;          // relation group
    const int fl  = lane & 15;          // feature slot: features fl*8..fl*8+7
    const int d = blockIdx.x * 4 + (t >> 6);
    if (d >= NN) return;

    float p1v[2], p2v[2];

#pragma unroll
    for (int pass = 0; pass < 2; ++pass) {
        const int r = pass * 4 + grp;
        float q1 = 0.f, q2 = 0.f;
        if (r < NR) {
            const int sbeg = offs[d * NR + r];
            const int send = offs[d * NR + r + 1];
            float a0 = 0.f, a1 = 0.f, a2 = 0.f, a3 = 0.f;
            float a4 = 0.f, a5 = 0.f, a6 = 0.f, a7 = 0.f;
            for (int j = sbeg; j < send; ++j) {
                int s = eidx[j];
                uint4 v = *(const uint4*)(nh2 + (size_t)s * 64 + fl * 4);
                a0 += bf_lo(v.x); a1 += bf_hi(v.x);
                a2 += bf_lo(v.y); a3 += bf_hi(v.y);
                a4 += bf_lo(v.z); a5 += bf_hi(v.z);
                a6 += bf_lo(v.w); a7 += bf_hi(v.w);
            }
            float sc = 1.0f / (1.0f + (float)(send - sbeg));
            a0 *= sc; a1 *= sc; a2 *= sc; a3 *= sc;
            a4 *= sc; a5 *= sc; a6 *= sc; a7 *= sc;
            uint4 o;
            o.x = pack2bf(a0, a1); o.y = pack2bf(a2, a3);
            o.z = pack2bf(a4, a5); o.w = pack2bf(a6, a7);
            *(uint4*)(aggp + ((size_t)r * NN + d) * 64 + fl * 4) = o;
            float4 wa = *(const float4*)(w1v + r * FD + fl * 8);
            float4 wb = *(const float4*)(w1v + r * FD + fl * 8 + 4);
            float4 wc = *(const float4*)(w2v + r * FD + fl * 8);
            float4 wd = *(const float4*)(w2v + r * FD + fl * 8 + 4);
            q1 = a0 * wa.x + a1 * wa.y + a2 * wa.z + a3 * wa.w
               + a4 * wb.x + a5 * wb.y + a6 * wb.z + a7 * wb.w;
            q2 = a0 * wc.x + a1 * wc.y + a2 * wc.z + a3 * wc.w
               + a4 * wd.x + a5 * wd.y + a6 * wd.z + a7 * wd.w;
        }
        // in-group (16-lane) reduction; stays within group for xor<16
#pragma unroll
        for (int off = 1; off < 16; off <<= 1) {
            q1 += __shfl_xor(q1, off, 64);
            q2 += __shfl_xor(q2, off, 64);
        }
        p1v[pass] = q1; p2v[pass] = q2;
    }

    // broadcast the 6 logits to all lanes
    float p1[NR], p2[NR];
#pragma unroll
    for (int r = 0; r < 4; ++r) {
        p1[r] = __shfl(p1v[0], r * 16, 64);
        p2[r] = __shfl(p2v[0], r * 16, 64);
    }
    p1[4] = __shfl(p1v[1], 0, 64);  p1[5] = __shfl(p1v[1], 16, 64);
    p2[4] = __shfl(p2v[1], 0, 64);  p2[5] = __shfl(p2v[1], 16, 64);

    float m1 = p1[0], m2 = p2[0];
#pragma unroll
    for (int r = 1; r < NR; ++r) { m1 = fmaxf(m1, p1[r]); m2 = fmaxf(m2, p2[r]); }
    float e1[NR], e2[NR], d1 = 0.f, d2 = 0.f;
#pragma unroll
    for (int r = 0; r < NR; ++r) {
        e1[r] = __expf(p1[r] - m1); d1 += e1[r];
        e2[r] = __expf(p2[r] - m2); d2 += e2[r];
    }
    d1 = 1.0f / d1; d2 = 1.0f / d2;
    if (lane == 0) {
#pragma unroll
        for (int r = 0; r < NR; ++r) {
            s1o[d * NR + r] = e1[r] * d1;
            s2o[d * NR + r] = e2[r] * d2;
        }
    }
}

// ---------------------------------------------------------------------------
// Fused output GEMM (bf16 MFMA):
//   out[n] = sum_r s1[n,r]*(agg_r[n] @ U1_r) + s2[n,r]*(agg_r[n] @ U2_r) + 6*bc
// ---------------------------------------------------------------------------
__global__ __launch_bounds__(256, 4) void k_fused(
    const unsigned* __restrict__ aggp,
    const float* __restrict__ s1, const float* __restrict__ s2,
    const short* __restrict__ Upk,
    const float* __restrict__ bc,
    float* __restrict__ out)
{
    __shared__ short Al[64 * 128];
    __shared__ float sl[2 * 64 * NR];
    const int n0 = blockIdx.x * 64;
    const int t = threadIdx.x;
    const int lane = t & 63;
    const int w = t >> 6;

    for (int i = t; i < 2 * 64 * NR; i += 256) {
        int h = i / (64 * NR);
        int rr = i % (64 * NR);
        int row = rr / NR, r = rr % NR;
        int n = n0 + row;
        float v = 0.f;
        if (n < NN) v = (h ? s2 : s1)[(size_t)n * NR + r];
        sl[i] = v;
    }

    f32x4 acc[8];
#pragma unroll
    for (int nt = 0; nt < 8; ++nt) acc[nt] = (f32x4){0.f, 0.f, 0.f, 0.f};

    const int m = w * 16 + (lane & 15);
    const int g = lane >> 4;

    for (int r = 0; r < NR; ++r) {
        __syncthreads();
        {
            int row = t >> 2, kq = t & 3;
            int n = n0 + row;
            const unsigned* src = aggp + ((size_t)r * NN + n) * 64 + kq * 16;
#pragma unroll
            for (int c = 0; c < 4; ++c) {
                uint4 v = make_uint4(0, 0, 0, 0);
                if (n < NN) v = *(const uint4*)(src + c * 4);
                int ks = kq * 32 + c * 8;
                int addr = row * 128 + (ks ^ ((row & 7) << 3));
                *(uint4*)&Al[addr] = v;
            }
        }
        __syncthreads();

#pragma unroll
        for (int h = 0; h < 2; ++h) {
            f32x4 ar[8];
#pragma unroll
            for (int nt = 0; nt < 8; ++nt) ar[nt] = (f32x4){0.f, 0.f, 0.f, 0.f};
#pragma unroll
            for (int kstep = 0; kstep < 4; ++kstep) {
                bf16x8 af = *(const bf16x8*)&Al[m * 128 + ((kstep * 32 + g * 8) ^ ((m & 7) << 3))];
                const short* Ub = Upk + (((size_t)(h * NR + r) * 4 + kstep) * 8) * 64 * 8 + lane * 8;
#pragma unroll
                for (int nt = 0; nt < 8; ++nt) {
                    bf16x8 bfr = *(const bf16x8*)(Ub + nt * 64 * 8);
                    ar[nt] = __builtin_amdgcn_mfma_f32_16x16x32_bf16(af, bfr, ar[nt], 0, 0, 0);
                }
            }
            float sv[4];
#pragma unroll
            for (int reg = 0; reg < 4; ++reg)
                sv[reg] = sl[h * 64 * NR + (w * 16 + (lane >> 4) * 4 + reg) * NR + r];
#pragma unroll
            for (int nt = 0; nt < 8; ++nt)
#pragma unroll
                for (int reg = 0; reg < 4; ++reg)
                    acc[nt][reg] += sv[reg] * ar[nt][reg];
        }
    }

    const int rowbase = n0 + w * 16 + (lane >> 4) * 4;
    const int col0 = lane & 15;
#pragma unroll
    for (int nt = 0; nt < 8; ++nt) {
        int col = nt * 16 + col0;
        float b6 = 6.0f * bc[col];
#pragma unroll
        for (int reg = 0; reg < 4; ++reg) {
            int n = rowbase + reg;
            if (n < NN) out[(size_t)n * FD + col] = acc[nt][reg] + b6;
        }
    }
}

// ---------------------------------------------------------------------------
extern "C" void kernel_launch(void* const* d_in, const int* in_sizes, int n_in,
                              void* d_out, int out_size, void* d_ws, size_t ws_size,
                              hipStream_t stream)
{
    const float* node_h = (const float*)d_in[0];
    const float* weight = (const float*)d_in[1];
    const float* att1   = (const float*)d_in[2];
    const float* att2   = (const float*)d_in[3];
    const float* Wc     = (const float*)d_in[4];
    const float* bc     = (const float*)d_in[5];
    const int* esrc = (const int*)d_in[6];
    const int* edst = (const int*)d_in[7];
    const int* erel = (const int*)d_in[8];
    float* out = (float*)d_out;

    char* wsp = (char*)d_ws;
    auto alloc = [&](size_t bytes) {
        char* p = wsp;
        wsp += (bytes + 255) & ~(size_t)255;
        return p;
    };
    unsigned* aggp = (unsigned*)alloc((size_t)NR * NN * 64 * 4);
    unsigned* nh2  = (unsigned*)alloc((size_t)NN * 64 * 4);
    short* Upk     = (short*)alloc((size_t)2 * NR * FD * FD * 2);
    float* w1      = (float*)alloc(NR * FD * 4);
    float* w2      = (float*)alloc(NR * FD * 4);
    float* s1      = (float*)alloc((size_t)NN * NR * 4);
    float* s2      = (float*)alloc((size_t)NN * NR * 4);
    int* offs      = (int*)alloc((size_t)(NS + 1 + 64) * 4);
    int* cursor    = (int*)alloc((size_t)(NS + 2048) * 4);  // also 'cnt'; padded for int4 tails
    int* bsum      = (int*)alloc(512 * 4);
    int* bpre      = (int*)alloc(512 * 4);
    int* eidx      = (int*)d_out;   // scratch in out's h-region; consumed by k_agg

    hipMemsetAsync(cursor, 0, (size_t)NS * sizeof(int), stream);

    k_hist<<<(NE + 255) / 256, 256, 0, stream>>>(edst, erel, cursor);
    k_bsum<<<MB, 256, 0, stream>>>(cursor, bsum);
    k_scanb<<<1, 512, 0, stream>>>(bsum, bpre);
    k_scan3<<<MB, 256, 0, stream>>>(cursor, bpre, offs, cursor);
    k_place<<<(NE + 255) / 256, 256, 0, stream>>>(esrc, edst, erel, cursor, eidx);

    k_cast<<<(NN * FD / 8 + 255) / 256, 256, 0, stream>>>(node_h, nh2);
    k_prep_w<<<NR, 256, 0, stream>>>(weight, att1, att2, w1, w2);
    k_prep_U<<<dim3(2, 2 * NR), 256, 0, stream>>>(weight, Wc, Upk);

    k_agg<<<(NN + 3) / 4, 256, 0, stream>>>(nh2, offs, eidx, w1, w2, aggp, s1, s2);

    k_fused<<<(NN + 63) / 64, 256, 0, stream>>>(aggp, s1, s2, Upk, bc, out);

    hipMemcpyAsync(out + (size_t)NN * FD, weight,
                   (size_t)NR * FD * FD * sizeof(float),
                   hipMemcpyDeviceToDevice, stream);
}

// Round 6
// 348.807 us; speedup vs baseline: 5.0618x; 1.0180x over previous
//
#include <hip/hip_runtime.h>

#define NN 50000
#define NE 800000
#define NR 6
#define FD 128
#define NS (NN * NR)              // segment count (dst,rel)
#define MB ((NS + 1023) / 1024)   // scan blocks (293)

typedef __attribute__((ext_vector_type(8))) short bf16x8;
typedef __attribute__((ext_vector_type(4))) float f32x4;

__device__ __forceinline__ unsigned short f2bf(float x) {
    unsigned u = __float_as_uint(x);
    u += 0x7FFFu + ((u >> 16) & 1u);          // round-to-nearest-even
    return (unsigned short)(u >> 16);
}
__device__ __forceinline__ unsigned pack2bf(float lo, float hi) {
    return (unsigned)f2bf(lo) | ((unsigned)f2bf(hi) << 16);
}
__device__ __forceinline__ float bf_lo(unsigned u) { return __uint_as_float(u << 16); }
__device__ __forceinline__ float bf_hi(unsigned u) { return __uint_as_float(u & 0xFFFF0000u); }

// ---------------------------------------------------------------------------
// node_h f32 -> packed bf16x2
// ---------------------------------------------------------------------------
__global__ __launch_bounds__(256) void k_cast(
    const float* __restrict__ node_h, unsigned* __restrict__ nh2)
{
    int i = (blockIdx.x * 256 + threadIdx.x) * 8;   // grid sized exactly
    float4 a = *(const float4*)(node_h + i);
    float4 b = *(const float4*)(node_h + i + 4);
    uint4 o;
    o.x = pack2bf(a.x, a.y); o.y = pack2bf(a.z, a.w);
    o.z = pack2bf(b.x, b.y); o.w = pack2bf(b.z, b.w);
    *(uint4*)(nh2 + i / 2) = o;
}

// ---------------------------------------------------------------------------
// Counting sort by seg = dst*NR + rel
// ---------------------------------------------------------------------------
__global__ __launch_bounds__(256) void k_hist(
    const int* __restrict__ edst, const int* __restrict__ erel,
    int* __restrict__ cnt)
{
    int e = blockIdx.x * 256 + threadIdx.x;
    if (e < NE) atomicAdd(cnt + edst[e] * NR + erel[e], 1);
}

// Stage 1: per-block (1024 elems) sums. Coalesced int4.
__global__ __launch_bounds__(256) void k_bsum(
    const int* __restrict__ cnt, int* __restrict__ bsum)
{
    __shared__ int red[256];
    const int b = blockIdx.x, t = threadIdx.x;
    int idx0 = b * 1024 + t * 4;
    int4 c = *(const int4*)(cnt + idx0);   // cnt is padded; mask below
    int s = 0;
    if (idx0 + 0 < NS) s += c.x;
    if (idx0 + 1 < NS) s += c.y;
    if (idx0 + 2 < NS) s += c.z;
    if (idx0 + 3 < NS) s += c.w;
    red[t] = s;
    __syncthreads();
    for (int off = 128; off > 0; off >>= 1) {
        if (t < off) red[t] += red[t + off];
        __syncthreads();
    }
    if (t == 0) bsum[b] = red[0];
}

// Stage 2: one block scans the MB block sums -> exclusive prefixes.
__global__ __launch_bounds__(512) void k_scanb(
    const int* __restrict__ bsum, int* __restrict__ bpre)
{
    __shared__ int s[512];
    const int t = threadIdx.x;
    int v = (t < MB) ? bsum[t] : 0;
    s[t] = v;
    __syncthreads();
    for (int off = 1; off < 512; off <<= 1) {
        int x = (t >= off) ? s[t - off] : 0;
        __syncthreads();
        if (t >= off) s[t] += x;
        __syncthreads();
    }
    bpre[t] = s[t] - v;   // exclusive
}

// Stage 3: per-block exclusive scan + bpre, writes offs and cursor. Coalesced.
__global__ __launch_bounds__(256) void k_scan3(
    const int* __restrict__ cnt, const int* __restrict__ bpre,
    int* __restrict__ offs, int* __restrict__ cursor)
{
    __shared__ int partial[256];
    const int b = blockIdx.x, t = threadIdx.x;
    int idx0 = b * 1024 + t * 4;
    int4 c = *(const int4*)(cnt + idx0);
    if (idx0 + 0 >= NS) c.x = 0;
    if (idx0 + 1 >= NS) c.y = 0;
    if (idx0 + 2 >= NS) c.z = 0;
    if (idx0 + 3 >= NS) c.w = 0;
    int tsum = c.x + c.y + c.z + c.w;
    partial[t] = tsum;
    __syncthreads();
    for (int off = 1; off < 256; off <<= 1) {
        int x = (t >= off) ? partial[t - off] : 0;
        __syncthreads();
        if (t >= off) partial[t] += x;
        __syncthreads();
    }
    int base = bpre[b] + partial[t] - tsum;
    int4 o;
    o.x = base;
    o.y = base + c.x;
    o.z = base + c.x + c.y;
    o.w = base + c.x + c.y + c.z;
    if (idx0 + 3 < NS) {
        *(int4*)(offs + idx0) = o;
        *(int4*)(cursor + idx0) = o;
    } else {
        int v[4] = {o.x, o.y, o.z, o.w};
        for (int k = 0; k < 4; ++k)
            if (idx0 + k < NS) { offs[idx0 + k] = v[k]; cursor[idx0 + k] = v[k]; }
    }
    if (b == 0 && t == 0) offs[NS] = NE;
}

__global__ __launch_bounds__(256) void k_place(
    const int* __restrict__ esrc, const int* __restrict__ edst,
    const int* __restrict__ erel, int* __restrict__ cursor,
    int* __restrict__ eidx)
{
    int e = blockIdx.x * 256 + threadIdx.x;
    if (e >= NE) return;
    int seg = edst[e] * NR + erel[e];
    int pos = atomicAdd(cursor + seg, 1);
    eidx[pos] = esrc[e];
}

// ---------------------------------------------------------------------------
// w1[r][f] = sum_o weight[r][f][o]*att1[o]; w2 likewise with att2.
// ---------------------------------------------------------------------------
__global__ __launch_bounds__(256) void k_prep_w(
    const float* __restrict__ weight,
    const float* __restrict__ att1, const float* __restrict__ att2,
    float* __restrict__ w1, float* __restrict__ w2)
{
    __shared__ float a1s[FD], a2s[FD];
    const int r = blockIdx.x;
    const int t = threadIdx.x;
    if (t < FD) { a1s[t] = att1[t]; a2s[t] = att2[t]; }
    __syncthreads();
    int f = t & 127;
    const float* av = (t < FD) ? a1s : a2s;
    float* wo = (t < FD) ? w1 : w2;
    const float* Wrow = weight + ((size_t)r * FD + f) * FD;
    float acc = 0.f;
#pragma unroll 8
    for (int o = 0; o < FD; ++o) acc += Wrow[o] * av[o];
    wo[r * FD + f] = acc;
}

// ---------------------------------------------------------------------------
// U_h[r] = W[r] @ Wc_h^T, packed bf16 in MFMA B-fragment order.
// ---------------------------------------------------------------------------
__global__ __launch_bounds__(256) void k_prep_U(
    const float* __restrict__ weight, const float* __restrict__ Wc,
    short* __restrict__ Upk)
{
    __shared__ float As[64 * 65];
    __shared__ float Bs[64 * 132];
    const int h  = blockIdx.y / NR;
    const int r  = blockIdx.y % NR;
    const int f0 = blockIdx.x * 64;
    const int t  = threadIdx.x;
    const int tm = t & 15, tn = t >> 4;

    float acc[4][8];
#pragma unroll
    for (int i = 0; i < 4; ++i)
#pragma unroll
        for (int j = 0; j < 8; ++j) acc[i][j] = 0.f;

    for (int kt = 0; kt < 2; ++kt) {
#pragma unroll
        for (int i = 0; i < 4; ++i) {
            int flat = i * 1024 + t * 4;
            int row = flat >> 6, k = flat & 63;
            float4 v = *(const float4*)(weight + ((size_t)r * FD + f0 + row) * FD + kt * 64 + k);
            float* p = As + row * 65 + k;
            p[0] = v.x; p[1] = v.y; p[2] = v.z; p[3] = v.w;
        }
#pragma unroll
        for (int i = 0; i < 8; ++i) {
            int flat4 = i * 256 + t;
            int o = flat4 >> 4, j4 = flat4 & 15;
            float4 v = *(const float4*)(Wc + (size_t)o * 256 + h * FD + kt * 64 + j4 * 4);
            float* p = Bs + (j4 * 4) * 132 + o;
            p[0] = v.x; p[132] = v.y; p[264] = v.z; p[396] = v.w;
        }
        __syncthreads();
#pragma unroll 4
        for (int k = 0; k < 64; ++k) {
            float aa[4];
#pragma unroll
            for (int i = 0; i < 4; ++i) aa[i] = As[(4 * tm + i) * 65 + k];
            float4 blo = *(const float4*)(Bs + k * 132 + 8 * tn);
            float4 bhi = *(const float4*)(Bs + k * 132 + 8 * tn + 4);
            float bb[8] = {blo.x, blo.y, blo.z, blo.w, bhi.x, bhi.y, bhi.z, bhi.w};
#pragma unroll
            for (int i = 0; i < 4; ++i)
#pragma unroll
                for (int j = 0; j < 8; ++j) acc[i][j] += aa[i] * bb[j];
        }
        __syncthreads();
    }

#pragma unroll
    for (int i = 0; i < 4; ++i)
#pragma unroll
        for (int j = 0; j < 8; ++j) {
            int f = f0 + 4 * tm + i, o = 8 * tn + j;
            int kstep = f >> 5, g = (f >> 3) & 3, jj = f & 7;
            int nt = o >> 4, ln = g * 16 + (o & 15);
            size_t sidx = ((((size_t)(h * NR + r) * 4 + kstep) * 8 + nt) * 64 + ln) * 8 + jj;
            Upk[sidx] = (short)f2bf(acc[i][j]);
        }
}

// ---------------------------------------------------------------------------
// Aggregate v2: one wave per dst; 4 groups of 16 lanes, each group owns one
// relation segment (pass 0: r=grp, pass 1: r=4+grp). Each lane covers 8
// features (uint4 = 16B load).
// ---------------------------------------------------------------------------
__global__ __launch_bounds__(256) void k_agg(
    const unsigned* __restrict__ nh2,   // [NN][64] packed bf16x2
    const int* __restrict__ offs,       // [NS+1]
    const int* __restrict__ eidx,       // [NE] src
    const float* __restrict__ w1v, const float* __restrict__ w2v,
    unsigned* __restrict__ aggp,        // [NR][NN][64]
    float* __restrict__ s1o, float* __restrict__ s2o)
{
    const int t = threadIdx.x;
    const int lane = t & 63;
    const int grp = lane >> 4;          // relation group
    const int fl  = lane & 15;          // feature slot: features fl*8..fl*8+7
    const int d = blockIdx.x * 4 + (t >> 6);
    if (d >= NN) return;

    float p1v[2], p2v[2];

#pragma unroll
    for (int pass = 0; pass < 2; ++pass) {
        const int r = pass * 4 + grp;
        float q1 = 0.f, q2 = 0.f;
        if (r < NR) {
            const int sbeg = offs[d * NR + r];
            const int send = offs[d * NR + r + 1];
            float a0 = 0.f, a1 = 0.f, a2 = 0.f, a3 = 0.f;
            float a4 = 0.f, a5 = 0.f, a6 = 0.f, a7 = 0.f;
            for (int j = sbeg; j < send; ++j) {
                int s = eidx[j];
                uint4 v = *(const uint4*)(nh2 + (size_t)s * 64 + fl * 4);
                a0 += bf_lo(v.x); a1 += bf_hi(v.x);
                a2 += bf_lo(v.y); a3 += bf_hi(v.y);
                a4 += bf_lo(v.z); a5 += bf_hi(v.z);
                a6 += bf_lo(v.w); a7 += bf_hi(v.w);
            }
            float sc = 1.0f / (1.0f + (float)(send - sbeg));
            a0 *= sc; a1 *= sc; a2 *= sc; a3 *= sc;
            a4 *= sc; a5 *= sc; a6 *= sc; a7 *= sc;
            uint4 o;
            o.x = pack2bf(a0, a1); o.y = pack2bf(a2, a3);
            o.z = pack2bf(a4, a5); o.w = pack2bf(a6, a7);
            *(uint4*)(aggp + ((size_t)r * NN + d) * 64 + fl * 4) = o;
            float4 wa = *(const float4*)(w1v + r * FD + fl * 8);
            float4 wb = *(const float4*)(w1v + r * FD + fl * 8 + 4);
            float4 wc = *(const float4*)(w2v + r * FD + fl * 8);
            float4 wd = *(const float4*)(w2v + r * FD + fl * 8 + 4);
            q1 = a0 * wa.x + a1 * wa.y + a2 * wa.z + a3 * wa.w
               + a4 * wb.x + a5 * wb.y + a6 * wb.z + a7 * wb.w;
            q2 = a0 * wc.x + a1 * wc.y + a2 * wc.z + a3 * wc.w
               + a4 * wd.x + a5 * wd.y + a6 * wd.z + a7 * wd.w;
        }
        // in-group (16-lane) reduction
#pragma unroll
        for (int off = 1; off < 16; off <<= 1) {
            q1 += __shfl_xor(q1, off, 64);
            q2 += __shfl_xor(q2, off, 64);
        }
        p1v[pass] = q1; p2v[pass] = q2;
    }

    // broadcast the 6 logits to all lanes
    float p1[NR], p2[NR];
#pragma unroll
    for (int r = 0; r < 4; ++r) {
        p1[r] = __shfl(p1v[0], r * 16, 64);
        p2[r] = __shfl(p2v[0], r * 16, 64);
    }
    p1[4] = __shfl(p1v[1], 0, 64);  p1[5] = __shfl(p1v[1], 16, 64);
    p2[4] = __shfl(p2v[1], 0, 64);  p2[5] = __shfl(p2v[1], 16, 64);

    float m1 = p1[0], m2 = p2[0];
#pragma unroll
    for (int r = 1; r < NR; ++r) { m1 = fmaxf(m1, p1[r]); m2 = fmaxf(m2, p2[r]); }
    float e1[NR], e2[NR], d1 = 0.f, d2 = 0.f;
#pragma unroll
    for (int r = 0; r < NR; ++r) {
        e1[r] = __expf(p1[r] - m1); d1 += e1[r];
        e2[r] = __expf(p2[r] - m2); d2 += e2[r];
    }
    d1 = 1.0f / d1; d2 = 1.0f / d2;
    if (lane == 0) {
#pragma unroll
        for (int r = 0; r < NR; ++r) {
            s1o[d * NR + r] = e1[r] * d1;
            s2o[d * NR + r] = e2[r] * d2;
        }
    }
}

// ---------------------------------------------------------------------------
// Fused output GEMM v2 (bf16 MFMA, barrier-free main loop):
//   out[n] = sum_r s1[n,r]*(agg_r[n] @ U1_r) + s2[n,r]*(agg_r[n] @ U2_r) + 6*bc
// A fragments read DIRECTLY from global (aggp rows are row-major 128 bf16 =
// exact A-frag layout: row=lane&15, k=(lane>>4)*8+j). No A-LDS, no barriers
// in the main loop. Grid split 2x over columns for occupancy (~6 blocks/CU).
// Block: 64 rows x 64 cols; wave w: rows w*16..w*16+15, 4 col-tiles of 16.
// ---------------------------------------------------------------------------
__global__ __launch_bounds__(256) void k_fused(
    const unsigned* __restrict__ aggp,  // [NR][NN][64] u32
    const float* __restrict__ s1, const float* __restrict__ s2,
    const short* __restrict__ Upk,
    const float* __restrict__ bc,
    float* __restrict__ out)
{
    __shared__ float sl[2 * 64 * NR];   // [h][row][r]
    const int n0 = blockIdx.x * 64;
    const int ch = blockIdx.y;          // column half (0/1)
    const int t = threadIdx.x;
    const int lane = t & 63;
    const int w = t >> 6;

    for (int i = t; i < 2 * 64 * NR; i += 256) {
        int h = i / (64 * NR);
        int rr = i % (64 * NR);
        int row = rr / NR, r = rr % NR;
        int n = n0 + row;
        float v = 0.f;
        if (n < NN) v = (h ? s2 : s1)[(size_t)n * NR + r];
        sl[i] = v;
    }
    __syncthreads();                    // only barrier in the kernel

    // A-fragment address: row (clamped for tail), k-offset from lane group
    const int mrow = min(n0 + w * 16 + (lane & 15), NN - 1);
    const int g = lane >> 4;
    const unsigned* arow = aggp + (size_t)mrow * 64 + g * 4;   // + r*NN*64 + kstep*16

    f32x4 acc[4];
#pragma unroll
    for (int nt = 0; nt < 4; ++nt) acc[nt] = (f32x4){0.f, 0.f, 0.f, 0.f};

    const int rl4 = w * 16 + (lane >> 4) * 4;   // local row base for epilogue

    for (int r = 0; r < NR; ++r) {
        // 4 independent A-fragment loads (shared by both heads)
        bf16x8 af[4];
#pragma unroll
        for (int kstep = 0; kstep < 4; ++kstep)
            af[kstep] = *(const bf16x8*)(arow + (size_t)r * (NN * 64) + kstep * 16);

#pragma unroll
        for (int h = 0; h < 2; ++h) {
            f32x4 ar[4];
#pragma unroll
            for (int nt = 0; nt < 4; ++nt) ar[nt] = (f32x4){0.f, 0.f, 0.f, 0.f};
            const short* Ub = Upk + ((size_t)(h * NR + r) * 4) * 8 * 512 + lane * 8;
#pragma unroll
            for (int kstep = 0; kstep < 4; ++kstep) {
#pragma unroll
                for (int nt = 0; nt < 4; ++nt) {
                    bf16x8 bfr = *(const bf16x8*)(Ub + ((size_t)kstep * 8 + ch * 4 + nt) * 512);
                    ar[nt] = __builtin_amdgcn_mfma_f32_16x16x32_bf16(af[kstep], bfr, ar[nt], 0, 0, 0);
                }
            }
            float sv[4];
#pragma unroll
            for (int reg = 0; reg < 4; ++reg)
                sv[reg] = sl[h * 64 * NR + (rl4 + reg) * NR + r];
#pragma unroll
            for (int nt = 0; nt < 4; ++nt)
#pragma unroll
                for (int reg = 0; reg < 4; ++reg)
                    acc[nt][reg] += sv[reg] * ar[nt][reg];
        }
    }

    const int rowbase = n0 + rl4;
    const int col0 = ch * 64 + (lane & 15);
#pragma unroll
    for (int nt = 0; nt < 4; ++nt) {
        int col = col0 + nt * 16;
        float b6 = 6.0f * bc[col];
#pragma unroll
        for (int reg = 0; reg < 4; ++reg) {
            int n = rowbase + reg;
            if (n < NN) out[(size_t)n * FD + col] = acc[nt][reg] + b6;
        }
    }
}

// ---------------------------------------------------------------------------
extern "C" void kernel_launch(void* const* d_in, const int* in_sizes, int n_in,
                              void* d_out, int out_size, void* d_ws, size_t ws_size,
                              hipStream_t stream)
{
    const float* node_h = (const float*)d_in[0];
    const float* weight = (const float*)d_in[1];
    const float* att1   = (const float*)d_in[2];
    const float* att2   = (const float*)d_in[3];
    const float* Wc     = (const float*)d_in[4];
    const float* bc     = (const float*)d_in[5];
    const int* esrc = (const int*)d_in[6];
    const int* edst = (const int*)d_in[7];
    const int* erel = (const int*)d_in[8];
    float* out = (float*)d_out;

    char* wsp = (char*)d_ws;
    auto alloc = [&](size_t bytes) {
        char* p = wsp;
        wsp += (bytes + 255) & ~(size_t)255;
        return p;
    };
    unsigned* aggp = (unsigned*)alloc((size_t)NR * NN * 64 * 4);
    unsigned* nh2  = (unsigned*)alloc((size_t)NN * 64 * 4);
    short* Upk     = (short*)alloc((size_t)2 * NR * FD * FD * 2);
    float* w1      = (float*)alloc(NR * FD * 4);
    float* w2      = (float*)alloc(NR * FD * 4);
    float* s1      = (float*)alloc((size_t)NN * NR * 4);
    float* s2      = (float*)alloc((size_t)NN * NR * 4);
    int* offs      = (int*)alloc((size_t)(NS + 1 + 64) * 4);
    int* cursor    = (int*)alloc((size_t)(NS + 2048) * 4);  // also 'cnt'; padded for int4 tails
    int* bsum      = (int*)alloc(512 * 4);
    int* bpre      = (int*)alloc(512 * 4);
    int* eidx      = (int*)d_out;   // scratch in out's h-region; consumed by k_agg

    hipMemsetAsync(cursor, 0, (size_t)NS * sizeof(int), stream);

    k_hist<<<(NE + 255) / 256, 256, 0, stream>>>(edst, erel, cursor);
    k_bsum<<<MB, 256, 0, stream>>>(cursor, bsum);
    k_scanb<<<1, 512, 0, stream>>>(bsum, bpre);
    k_scan3<<<MB, 256, 0, stream>>>(cursor, bpre, offs, cursor);
    k_place<<<(NE + 255) / 256, 256, 0, stream>>>(esrc, edst, erel, cursor, eidx);

    k_cast<<<(NN * FD / 8 + 255) / 256, 256, 0, stream>>>(node_h, nh2);
    k_prep_w<<<NR, 256, 0, stream>>>(weight, att1, att2, w1, w2);
    k_prep_U<<<dim3(2, 2 * NR), 256, 0, stream>>>(weight, Wc, Upk);

    k_agg<<<(NN + 3) / 4, 256, 0, stream>>>(nh2, offs, eidx, w1, w2, aggp, s1, s2);

    dim3 gf((NN + 63) / 64, 2);
    k_fused<<<gf, 256, 0, stream>>>(aggp, s1, s2, Upk, bc, out);

    hipMemcpyAsync(out + (size_t)NN * FD, weight,
                   (size_t)NR * FD * FD * sizeof(float),
                   hipMemcpyDeviceToDevice, stream);
}

// Round 7
// 341.495 us; speedup vs baseline: 5.1702x; 1.0214x over previous
//
#include <hip/hip_runtime.h>

#define NN 50000
#define NE 800000
#define NR 6
#define FD 128
#define NS (NN * NR)              // segment count (dst,rel)
#define MB ((NS + 1023) / 1024)   // scan blocks (293)

typedef __attribute__((ext_vector_type(8))) short bf16x8;
typedef __attribute__((ext_vector_type(4))) float f32x4;

__device__ __forceinline__ unsigned short f2bf(float x) {
    unsigned u = __float_as_uint(x);
    u += 0x7FFFu + ((u >> 16) & 1u);          // round-to-nearest-even
    return (unsigned short)(u >> 16);
}
__device__ __forceinline__ unsigned pack2bf(float lo, float hi) {
    return (unsigned)f2bf(lo) | ((unsigned)f2bf(hi) << 16);
}
__device__ __forceinline__ float bf_lo(unsigned u) { return __uint_as_float(u << 16); }
__device__ __forceinline__ float bf_hi(unsigned u) { return __uint_as_float(u & 0xFFFF0000u); }

// ---------------------------------------------------------------------------
// node_h f32 -> packed bf16x2
// ---------------------------------------------------------------------------
__global__ __launch_bounds__(256) void k_cast(
    const float* __restrict__ node_h, unsigned* __restrict__ nh2)
{
    int i = (blockIdx.x * 256 + threadIdx.x) * 8;   // grid sized exactly
    float4 a = *(const float4*)(node_h + i);
    float4 b = *(const float4*)(node_h + i + 4);
    uint4 o;
    o.x = pack2bf(a.x, a.y); o.y = pack2bf(a.z, a.w);
    o.z = pack2bf(b.x, b.y); o.w = pack2bf(b.z, b.w);
    *(uint4*)(nh2 + i / 2) = o;
}

// ---------------------------------------------------------------------------
// Counting sort by seg = dst*NR + rel
// ---------------------------------------------------------------------------
__global__ __launch_bounds__(256) void k_hist(
    const int* __restrict__ edst, const int* __restrict__ erel,
    int* __restrict__ cnt)
{
    int e = blockIdx.x * 256 + threadIdx.x;
    if (e < NE) atomicAdd(cnt + edst[e] * NR + erel[e], 1);
}

// Stage 1: per-block (1024 elems) sums. Coalesced int4.
__global__ __launch_bounds__(256) void k_bsum(
    const int* __restrict__ cnt, int* __restrict__ bsum)
{
    __shared__ int red[256];
    const int b = blockIdx.x, t = threadIdx.x;
    int idx0 = b * 1024 + t * 4;
    int4 c = *(const int4*)(cnt + idx0);   // cnt is padded; mask below
    int s = 0;
    if (idx0 + 0 < NS) s += c.x;
    if (idx0 + 1 < NS) s += c.y;
    if (idx0 + 2 < NS) s += c.z;
    if (idx0 + 3 < NS) s += c.w;
    red[t] = s;
    __syncthreads();
    for (int off = 128; off > 0; off >>= 1) {
        if (t < off) red[t] += red[t + off];
        __syncthreads();
    }
    if (t == 0) bsum[b] = red[0];
}

// Stage 2: one block scans the MB block sums -> exclusive prefixes.
__global__ __launch_bounds__(512) void k_scanb(
    const int* __restrict__ bsum, int* __restrict__ bpre)
{
    __shared__ int s[512];
    const int t = threadIdx.x;
    int v = (t < MB) ? bsum[t] : 0;
    s[t] = v;
    __syncthreads();
    for (int off = 1; off < 512; off <<= 1) {
        int x = (t >= off) ? s[t - off] : 0;
        __syncthreads();
        if (t >= off) s[t] += x;
        __syncthreads();
    }
    bpre[t] = s[t] - v;   // exclusive
}

// Stage 3: per-block exclusive scan + bpre, writes offs and cursor. Coalesced.
__global__ __launch_bounds__(256) void k_scan3(
    const int* __restrict__ cnt, const int* __restrict__ bpre,
    int* __restrict__ offs, int* __restrict__ cursor)
{
    __shared__ int partial[256];
    const int b = blockIdx.x, t = threadIdx.x;
    int idx0 = b * 1024 + t * 4;
    int4 c = *(const int4*)(cnt + idx0);
    if (idx0 + 0 >= NS) c.x = 0;
    if (idx0 + 1 >= NS) c.y = 0;
    if (idx0 + 2 >= NS) c.z = 0;
    if (idx0 + 3 >= NS) c.w = 0;
    int tsum = c.x + c.y + c.z + c.w;
    partial[t] = tsum;
    __syncthreads();
    for (int off = 1; off < 256; off <<= 1) {
        int x = (t >= off) ? partial[t - off] : 0;
        __syncthreads();
        if (t >= off) partial[t] += x;
        __syncthreads();
    }
    int base = bpre[b] + partial[t] - tsum;
    int4 o;
    o.x = base;
    o.y = base + c.x;
    o.z = base + c.x + c.y;
    o.w = base + c.x + c.y + c.z;
    if (idx0 + 3 < NS) {
        *(int4*)(offs + idx0) = o;
        *(int4*)(cursor + idx0) = o;
    } else {
        int v[4] = {o.x, o.y, o.z, o.w};
        for (int k = 0; k < 4; ++k)
            if (idx0 + k < NS) { offs[idx0 + k] = v[k]; cursor[idx0 + k] = v[k]; }
    }
    if (b == 0 && t == 0) offs[NS] = NE;
}

__global__ __launch_bounds__(256) void k_place(
    const int* __restrict__ esrc, const int* __restrict__ edst,
    const int* __restrict__ erel, int* __restrict__ cursor,
    int* __restrict__ eidx)
{
    int e = blockIdx.x * 256 + threadIdx.x;
    if (e >= NE) return;
    int seg = edst[e] * NR + erel[e];
    int pos = atomicAdd(cursor + seg, 1);
    eidx[pos] = esrc[e];
}

// ---------------------------------------------------------------------------
// w1[r][f] = sum_o weight[r][f][o]*att1[o]; w2 likewise with att2.
// ---------------------------------------------------------------------------
__global__ __launch_bounds__(256) void k_prep_w(
    const float* __restrict__ weight,
    const float* __restrict__ att1, const float* __restrict__ att2,
    float* __restrict__ w1, float* __restrict__ w2)
{
    __shared__ float a1s[FD], a2s[FD];
    const int r = blockIdx.x;
    const int t = threadIdx.x;
    if (t < FD) { a1s[t] = att1[t]; a2s[t] = att2[t]; }
    __syncthreads();
    int f = t & 127;
    const float* av = (t < FD) ? a1s : a2s;
    float* wo = (t < FD) ? w1 : w2;
    const float* Wrow = weight + ((size_t)r * FD + f) * FD;
    float acc = 0.f;
#pragma unroll 8
    for (int o = 0; o < FD; ++o) acc += Wrow[o] * av[o];
    wo[r * FD + f] = acc;
}

// ---------------------------------------------------------------------------
// U_h[r] = W[r] @ Wc_h^T, packed bf16 in MFMA B-fragment order.
// ---------------------------------------------------------------------------
__global__ __launch_bounds__(256) void k_prep_U(
    const float* __restrict__ weight, const float* __restrict__ Wc,
    short* __restrict__ Upk)
{
    __shared__ float As[64 * 65];
    __shared__ float Bs[64 * 132];
    const int h  = blockIdx.y / NR;
    const int r  = blockIdx.y % NR;
    const int f0 = blockIdx.x * 64;
    const int t  = threadIdx.x;
    const int tm = t & 15, tn = t >> 4;

    float acc[4][8];
#pragma unroll
    for (int i = 0; i < 4; ++i)
#pragma unroll
        for (int j = 0; j < 8; ++j) acc[i][j] = 0.f;

    for (int kt = 0; kt < 2; ++kt) {
#pragma unroll
        for (int i = 0; i < 4; ++i) {
            int flat = i * 1024 + t * 4;
            int row = flat >> 6, k = flat & 63;
            float4 v = *(const float4*)(weight + ((size_t)r * FD + f0 + row) * FD + kt * 64 + k);
            float* p = As + row * 65 + k;
            p[0] = v.x; p[1] = v.y; p[2] = v.z; p[3] = v.w;
        }
#pragma unroll
        for (int i = 0; i < 8; ++i) {
            int flat4 = i * 256 + t;
            int o = flat4 >> 4, j4 = flat4 & 15;
            float4 v = *(const float4*)(Wc + (size_t)o * 256 + h * FD + kt * 64 + j4 * 4);
            float* p = Bs + (j4 * 4) * 132 + o;
            p[0] = v.x; p[132] = v.y; p[264] = v.z; p[396] = v.w;
        }
        __syncthreads();
#pragma unroll 4
        for (int k = 0; k < 64; ++k) {
            float aa[4];
#pragma unroll
            for (int i = 0; i < 4; ++i) aa[i] = As[(4 * tm + i) * 65 + k];
            float4 blo = *(const float4*)(Bs + k * 132 + 8 * tn);
            float4 bhi = *(const float4*)(Bs + k * 132 + 8 * tn + 4);
            float bb[8] = {blo.x, blo.y, blo.z, blo.w, bhi.x, bhi.y, bhi.z, bhi.w};
#pragma unroll
            for (int i = 0; i < 4; ++i)
#pragma unroll
                for (int j = 0; j < 8; ++j) acc[i][j] += aa[i] * bb[j];
        }
        __syncthreads();
    }

#pragma unroll
    for (int i = 0; i < 4; ++i)
#pragma unroll
        for (int j = 0; j < 8; ++j) {
            int f = f0 + 4 * tm + i, o = 8 * tn + j;
            int kstep = f >> 5, g = (f >> 3) & 3, jj = f & 7;
            int nt = o >> 4, ln = g * 16 + (o & 15);
            size_t sidx = ((((size_t)(h * NR + r) * 4 + kstep) * 8 + nt) * 64 + ln) * 8 + jj;
            Upk[sidx] = (short)f2bf(acc[i][j]);
        }
}

// ---------------------------------------------------------------------------
// Aggregate v2: one wave per dst; 4 groups of 16 lanes, each group owns one
// relation segment (pass 0: r=grp, pass 1: r=4+grp). Each lane covers 8
// features (uint4 = 16B load).
// ---------------------------------------------------------------------------
__global__ __launch_bounds__(256) void k_agg(
    const unsigned* __restrict__ nh2,   // [NN][64] packed bf16x2
    const int* __restrict__ offs,       // [NS+1]
    const int* __restrict__ eidx,       // [NE] src
    const float* __restrict__ w1v, const float* __restrict__ w2v,
    unsigned* __restrict__ aggp,        // [NR][NN][64]
    float* __restrict__ s1o, float* __restrict__ s2o)
{
    const int t = threadIdx.x;
    const int lane = t & 63;
    const int grp = lane >> 4;          // relation group
    const int fl  = lane & 15;          // feature slot: features fl*8..fl*8+7
    const int d = blockIdx.x * 4 + (t >> 6);
    if (d >= NN) return;

    float p1v[2], p2v[2];

#pragma unroll
    for (int pass = 0; pass < 2; ++pass) {
        const int r = pass * 4 + grp;
        float q1 = 0.f, q2 = 0.f;
        if (r < NR) {
            const int sbeg = offs[d * NR + r];
            const int send = offs[d * NR + r + 1];
            float a0 = 0.f, a1 = 0.f, a2 = 0.f, a3 = 0.f;
            float a4 = 0.f, a5 = 0.f, a6 = 0.f, a7 = 0.f;
            for (int j = sbeg; j < send; ++j) {
                int s = eidx[j];
                uint4 v = *(const uint4*)(nh2 + (size_t)s * 64 + fl * 4);
                a0 += bf_lo(v.x); a1 += bf_hi(v.x);
                a2 += bf_lo(v.y); a3 += bf_hi(v.y);
                a4 += bf_lo(v.z); a5 += bf_hi(v.z);
                a6 += bf_lo(v.w); a7 += bf_hi(v.w);
            }
            float sc = 1.0f / (1.0f + (float)(send - sbeg));
            a0 *= sc; a1 *= sc; a2 *= sc; a3 *= sc;
            a4 *= sc; a5 *= sc; a6 *= sc; a7 *= sc;
            uint4 o;
            o.x = pack2bf(a0, a1); o.y = pack2bf(a2, a3);
            o.z = pack2bf(a4, a5); o.w = pack2bf(a6, a7);
            *(uint4*)(aggp + ((size_t)r * NN + d) * 64 + fl * 4) = o;
            float4 wa = *(const float4*)(w1v + r * FD + fl * 8);
            float4 wb = *(const float4*)(w1v + r * FD + fl * 8 + 4);
            float4 wc = *(const float4*)(w2v + r * FD + fl * 8);
            float4 wd = *(const float4*)(w2v + r * FD + fl * 8 + 4);
            q1 = a0 * wa.x + a1 * wa.y + a2 * wa.z + a3 * wa.w
               + a4 * wb.x + a5 * wb.y + a6 * wb.z + a7 * wb.w;
            q2 = a0 * wc.x + a1 * wc.y + a2 * wc.z + a3 * wc.w
               + a4 * wd.x + a5 * wd.y + a6 * wd.z + a7 * wd.w;
        }
        // in-group (16-lane) reduction
#pragma unroll
        for (int off = 1; off < 16; off <<= 1) {
            q1 += __shfl_xor(q1, off, 64);
            q2 += __shfl_xor(q2, off, 64);
        }
        p1v[pass] = q1; p2v[pass] = q2;
    }

    // broadcast the 6 logits to all lanes
    float p1[NR], p2[NR];
#pragma unroll
    for (int r = 0; r < 4; ++r) {
        p1[r] = __shfl(p1v[0], r * 16, 64);
        p2[r] = __shfl(p2v[0], r * 16, 64);
    }
    p1[4] = __shfl(p1v[1], 0, 64);  p1[5] = __shfl(p1v[1], 16, 64);
    p2[4] = __shfl(p2v[1], 0, 64);  p2[5] = __shfl(p2v[1], 16, 64);

    float m1 = p1[0], m2 = p2[0];
#pragma unroll
    for (int r = 1; r < NR; ++r) { m1 = fmaxf(m1, p1[r]); m2 = fmaxf(m2, p2[r]); }
    float e1[NR], e2[NR], d1 = 0.f, d2 = 0.f;
#pragma unroll
    for (int r = 0; r < NR; ++r) {
        e1[r] = __expf(p1[r] - m1); d1 += e1[r];
        e2[r] = __expf(p2[r] - m2); d2 += e2[r];
    }
    d1 = 1.0f / d1; d2 = 1.0f / d2;
    if (lane == 0) {
#pragma unroll
        for (int r = 0; r < NR; ++r) {
            s1o[d * NR + r] = e1[r] * d1;
            s2o[d * NR + r] = e2[r] * d2;
        }
    }
}

// ---------------------------------------------------------------------------
// Fused output GEMM v3 (bf16 MFMA, barrier-free main loop, occupancy-bound):
//   out[n] = sum_r s1[n,r]*(agg_r[n] @ U1_r) + s2[n,r]*(agg_r[n] @ U2_r) + 6*bc
// Wave = 32 rows x 64 cols (2 row-frags -> each B-frag load feeds 2 MFMAs).
// Block = 4 waves = 64 rows x 128 cols. Grid = 782. __launch_bounds__(256,4)
// caps VGPR at 128 -> 4 waves/SIMD for latency hiding (round-6 fix: 172 VGPR
// at plain bounds collapsed occupancy to 9%).
// ---------------------------------------------------------------------------
__global__ __launch_bounds__(256, 4) void k_fused(
    const unsigned* __restrict__ aggp,  // [NR][NN][64] u32
    const float* __restrict__ s1, const float* __restrict__ s2,
    const short* __restrict__ Upk,
    const float* __restrict__ bc,
    float* __restrict__ out)
{
    __shared__ float sl[2 * 64 * NR];   // [h][row][r]
    const int n0 = blockIdx.x * 64;
    const int t = threadIdx.x;
    const int lane = t & 63;
    const int w = t >> 6;
    const int wrow = (w & 1) * 32;      // wave row base (local)
    const int wcol = (w >> 1) * 4;      // wave col-tile base (nt8 units)

    for (int i = t; i < 2 * 64 * NR; i += 256) {
        int h = i / (64 * NR);
        int rr = i % (64 * NR);
        int row = rr / NR, r = rr % NR;
        int n = n0 + row;
        float v = 0.f;
        if (n < NN) v = (h ? s2 : s1)[(size_t)n * NR + r];
        sl[i] = v;
    }
    __syncthreads();                    // only barrier in the kernel

    const int g = lane >> 4;
    const int m0 = n0 + wrow + (lane & 15);
    const unsigned* arow0 = aggp + (size_t)min(m0, NN - 1) * 64 + g * 4;
    const unsigned* arow1 = aggp + (size_t)min(m0 + 16, NN - 1) * 64 + g * 4;

    f32x4 acc[2][4];
#pragma unroll
    for (int rf = 0; rf < 2; ++rf)
#pragma unroll
        for (int nt = 0; nt < 4; ++nt) acc[rf][nt] = (f32x4){0.f, 0.f, 0.f, 0.f};

    const int rq = (lane >> 4) * 4;     // row offset within 16 from C-layout

    for (int r = 0; r < NR; ++r) {
        // A fragments for both row-frags, all 4 k-steps (reused across h)
        bf16x8 af[2][4];
#pragma unroll
        for (int kstep = 0; kstep < 4; ++kstep) {
            af[0][kstep] = *(const bf16x8*)(arow0 + (size_t)r * (NN * 64) + kstep * 16);
            af[1][kstep] = *(const bf16x8*)(arow1 + (size_t)r * (NN * 64) + kstep * 16);
        }

#pragma unroll
        for (int h = 0; h < 2; ++h) {
            f32x4 ar[2][4];
#pragma unroll
            for (int rf = 0; rf < 2; ++rf)
#pragma unroll
                for (int nt = 0; nt < 4; ++nt) ar[rf][nt] = (f32x4){0.f, 0.f, 0.f, 0.f};
            const short* Ub = Upk + ((size_t)(h * NR + r) * 4) * 8 * 512 + lane * 8;
#pragma unroll
            for (int kstep = 0; kstep < 4; ++kstep) {
#pragma unroll
                for (int nt = 0; nt < 4; ++nt) {
                    bf16x8 bfr = *(const bf16x8*)(Ub + ((size_t)kstep * 8 + wcol + nt) * 512);
                    ar[0][nt] = __builtin_amdgcn_mfma_f32_16x16x32_bf16(af[0][kstep], bfr, ar[0][nt], 0, 0, 0);
                    ar[1][nt] = __builtin_amdgcn_mfma_f32_16x16x32_bf16(af[1][kstep], bfr, ar[1][nt], 0, 0, 0);
                }
            }
#pragma unroll
            for (int rf = 0; rf < 2; ++rf) {
                float sv[4];
#pragma unroll
                for (int reg = 0; reg < 4; ++reg)
                    sv[reg] = sl[h * 64 * NR + (wrow + rf * 16 + rq + reg) * NR + r];
#pragma unroll
                for (int nt = 0; nt < 4; ++nt)
#pragma unroll
                    for (int reg = 0; reg < 4; ++reg)
                        acc[rf][nt][reg] += sv[reg] * ar[rf][nt][reg];
            }
        }
    }

    const int col0 = wcol * 16 + (lane & 15);
#pragma unroll
    for (int rf = 0; rf < 2; ++rf) {
        int rowbase = n0 + wrow + rf * 16 + rq;
#pragma unroll
        for (int nt = 0; nt < 4; ++nt) {
            int col = col0 + nt * 16;
            float b6 = 6.0f * bc[col];
#pragma unroll
            for (int reg = 0; reg < 4; ++reg) {
                int n = rowbase + reg;
                if (n < NN) out[(size_t)n * FD + col] = acc[rf][nt][reg] + b6;
            }
        }
    }
}

// ---------------------------------------------------------------------------
extern "C" void kernel_launch(void* const* d_in, const int* in_sizes, int n_in,
                              void* d_out, int out_size, void* d_ws, size_t ws_size,
                              hipStream_t stream)
{
    const float* node_h = (const float*)d_in[0];
    const float* weight = (const float*)d_in[1];
    const float* att1   = (const float*)d_in[2];
    const float* att2   = (const float*)d_in[3];
    const float* Wc     = (const float*)d_in[4];
    const float* bc     = (const float*)d_in[5];
    const int* esrc = (const int*)d_in[6];
    const int* edst = (const int*)d_in[7];
    const int* erel = (const int*)d_in[8];
    float* out = (float*)d_out;

    char* wsp = (char*)d_ws;
    auto alloc = [&](size_t bytes) {
        char* p = wsp;
        wsp += (bytes + 255) & ~(size_t)255;
        return p;
    };
    unsigned* aggp = (unsigned*)alloc((size_t)NR * NN * 64 * 4);
    unsigned* nh2  = (unsigned*)alloc((size_t)NN * 64 * 4);
    short* Upk     = (short*)alloc((size_t)2 * NR * FD * FD * 2);
    float* w1      = (float*)alloc(NR * FD * 4);
    float* w2      = (float*)alloc(NR * FD * 4);
    float* s1      = (float*)alloc((size_t)NN * NR * 4);
    float* s2      = (float*)alloc((size_t)NN * NR * 4);
    int* offs      = (int*)alloc((size_t)(NS + 1 + 64) * 4);
    int* cursor    = (int*)alloc((size_t)(NS + 2048) * 4);  // also 'cnt'; padded for int4 tails
    int* bsum      = (int*)alloc(512 * 4);
    int* bpre      = (int*)alloc(512 * 4);
    int* eidx      = (int*)d_out;   // scratch in out's h-region; consumed by k_agg

    hipMemsetAsync(cursor, 0, (size_t)NS * sizeof(int), stream);

    k_hist<<<(NE + 255) / 256, 256, 0, stream>>>(edst, erel, cursor);
    k_bsum<<<MB, 256, 0, stream>>>(cursor, bsum);
    k_scanb<<<1, 512, 0, stream>>>(bsum, bpre);
    k_scan3<<<MB, 256, 0, stream>>>(cursor, bpre, offs, cursor);
    k_place<<<(NE + 255) / 256, 256, 0, stream>>>(esrc, edst, erel, cursor, eidx);

    k_cast<<<(NN * FD / 8 + 255) / 256, 256, 0, stream>>>(node_h, nh2);
    k_prep_w<<<NR, 256, 0, stream>>>(weight, att1, att2, w1, w2);
    k_prep_U<<<dim3(2, 2 * NR), 256, 0, stream>>>(weight, Wc, Upk);

    k_agg<<<(NN + 3) / 4, 256, 0, stream>>>(nh2, offs, eidx, w1, w2, aggp, s1, s2);

    k_fused<<<(NN + 63) / 64, 256, 0, stream>>>(aggp, s1, s2, Upk, bc, out);

    hipMemcpyAsync(out + (size_t)NN * FD, weight,
                   (size_t)NR * FD * FD * sizeof(float),
                   hipMemcpyDeviceToDevice, stream);
}